// Round 6
// baseline (251.569 us; speedup 1.0000x reference)
//
#include <hip/hip_runtime.h>
#include <math.h>

// Shapes: B=8, H=W=64, C=256, HEADS=8, d=32, WS=8, SS=4, K=9
// NTOK = 32768 tokens; 512 windows of 64 tokens.
// Conv = implicit GEMM: M=32768 px, N=256 oc, K=2304 (f16 MFMA, B direct-reg).
// QKV  = GEMM M=32768, N=768, K=256 (bf16 MFMA, fp16 outputs).
// Attn = per-window MFMA fp16: S^T = K·Q^T, O = P·V^T. 1 wave = 1 head.
// Proj = GEMM M=32768, N=256, K=256 (bf16 MFMA, fp16 feat output).

#define NFLOAT_BUF 8388608  // 32768*256

typedef float f32x4 __attribute__((ext_vector_type(4)));
typedef __bf16 bf16x8 __attribute__((ext_vector_type(8)));
typedef _Float16 f16x8 __attribute__((ext_vector_type(8)));

__device__ inline unsigned pack2_bf16(float a, float b) {
    union { float f; unsigned u; } ua, ub;
    ua.f = a; ub.f = b;
    unsigned ra = (ua.u + 0x7FFFu + ((ua.u >> 16) & 1u)) >> 16;
    unsigned rb = (ub.u + 0x7FFFu + ((ub.u >> 16) & 1u)) & 0xFFFF0000u;
    return (ra & 0xFFFFu) | rb;
}
__device__ inline unsigned short pack1_bf16(float a) {
    union { float f; unsigned u; } v;
    v.f = a;
    return (unsigned short)((v.u + 0x7FFFu + ((v.u >> 16) & 1u)) >> 16);
}

// ---------------------------------------------------------------------------
// fp32 -> bf16 bulk convert (8 elems/thread)
// ---------------------------------------------------------------------------
__global__ __launch_bounds__(256) void cvt_bf16_kernel(const float* __restrict__ src,
                                                       unsigned short* __restrict__ dst,
                                                       int n8) {
    int t = blockIdx.x * 256 + threadIdx.x;
    if (t >= n8) return;
    const float4* s = (const float4*)(src + (size_t)t * 8);
    float4 a = s[0], b = s[1];
    uint4 o;
    o.x = pack2_bf16(a.x, a.y); o.y = pack2_bf16(a.z, a.w);
    o.z = pack2_bf16(b.x, b.y); o.w = pack2_bf16(b.z, b.w);
    *(uint4*)(dst + (size_t)t * 8) = o;
}

// ---------------------------------------------------------------------------
// dsc_weight (O=256, I=256, K=9) -> wT2h fp16 [o][kk=k*256+i]
// ---------------------------------------------------------------------------
__global__ __launch_bounds__(256) void transpose_w_kernel(const float* __restrict__ w,
                                                          _Float16* __restrict__ wT) {
    int t = blockIdx.x * 256 + threadIdx.x;   // < 589824
    int o = t / 2304;
    int kk = t - o * 2304;
    int k = kk >> 8, i = kk & 255;
    wT[t] = (_Float16)w[(o * 256 + i) * 9 + k];
}

// ---------------------------------------------------------------------------
// snake coordinate map -> ymap[b][wd*9+k][hd]
// ---------------------------------------------------------------------------
__global__ __launch_bounds__(256) void ymap_kernel(const float* __restrict__ offset,
                                                   float* __restrict__ ymap) {
    int t = blockIdx.x * 256 + threadIdx.x;   // < 32768
    int hd = t & 63;
    int wd = (t >> 6) & 63;
    int b  = t >> 12;
    const float* op = offset + ((size_t)(b * 18) * 64 + wd) * 64 + hd;
    float yo[9];
    #pragma unroll
    for (int k = 0; k < 9; ++k) yo[k] = op[(size_t)k * 4096];
    float cum[9];
    cum[4] = 0.0f;
    float s = 0.0f;
    for (int j = 3; j >= 0; --j) { s += yo[j]; cum[j] = s; }
    s = 0.0f;
    for (int j = 5; j < 9; ++j) { s += yo[j]; cum[j] = s; }
    float wdf = (float)wd;
    float* yp = ymap + ((size_t)(b * 576 + wd * 9)) * 64 + hd;
    #pragma unroll
    for (int k = 0; k < 9; ++k) yp[(size_t)k * 64] = wdf + cum[k];
}

// ---------------------------------------------------------------------------
// QKV GEMM via bf16 MFMA. Block = 64 M-rows x 256 N. grid (3, 512).
// Outputs fp16: q,k as [win*8+h][l][32]; v transposed [win*8+h][32][64].
// ---------------------------------------------------------------------------
__global__ __launch_bounds__(256) void qkv_mfma_kernel(
    const unsigned short* __restrict__ xb, const unsigned short* __restrict__ wb,
    const float* __restrict__ qkv_b,
    _Float16* __restrict__ qh, _Float16* __restrict__ kh, _Float16* __restrict__ vt) {

    __shared__ __align__(16) char Asb[8192];    // 64 rows * 128B
    __shared__ __align__(16) char Bsb[32768];   // 256 rows * 128B
    __shared__ unsigned rowoff[64];

    int nb = blockIdx.x;          // 0..2  (q / k / v)
    int m0 = blockIdx.y * 64;
    int tid = threadIdx.x;
    int lane = tid & 63, w = tid >> 6;
    int gw = m0 >> 6;             // global window

    if (tid < 64) {
        int l = tid;
        int b = gw >> 6, win = gw & 63;
        int rh = ((win >> 3) << 3) + (l >> 3);
        int rw = ((win & 7) << 3) + (l & 7);
        int sh = (rh + 4) & 63, sw = (rw + 4) & 63;
        rowoff[l] = (unsigned)(((b * 64 + sh) * 64 + sw) * 512);  // byte offset
    }

    f32x4 acc[4][4];
    #pragma unroll
    for (int m = 0; m < 4; ++m)
        #pragma unroll
        for (int n = 0; n < 4; ++n) {
            f32x4 z = {0.0f, 0.0f, 0.0f, 0.0f};
            acc[m][n] = z;
        }

    const char* xc = (const char*)xb;
    const char* wc = (const char*)wb;
    int rA = (lane & 15) * 128;
    int u0 = (((lane >> 4)    ) ^ (lane & 7)) << 4;
    int u1 = ((4 + (lane >> 4)) ^ (lane & 7)) << 4;

    __syncthreads();

    for (int c = 0; c < 4; ++c) {   // K chunks of 64
        #pragma unroll
        for (int r = 0; r < 2; ++r) {
            int pos = r * 256 + tid;
            int row = pos >> 3, u = pos & 7;
            const char* src = xc + rowoff[row] + c * 128 + ((u ^ (row & 7)) << 4);
            __builtin_amdgcn_global_load_lds(
                (const __attribute__((address_space(1))) unsigned int*)src,
                (__attribute__((address_space(3))) unsigned int*)(Asb + pos * 16),
                16, 0, 0);
        }
        #pragma unroll
        for (int r = 0; r < 8; ++r) {
            int pos = r * 256 + tid;
            int n = pos >> 3, u = pos & 7;
            const char* src = wc + (size_t)(nb * 256 + n) * 512 + c * 128 + ((u ^ (n & 7)) << 4);
            __builtin_amdgcn_global_load_lds(
                (const __attribute__((address_space(1))) unsigned int*)src,
                (__attribute__((address_space(3))) unsigned int*)(Bsb + pos * 16),
                16, 0, 0);
        }
        __syncthreads();

        bf16x8 av[4][2], bv[4][2];
        #pragma unroll
        for (int m = 0; m < 4; ++m) {
            av[m][0] = *(const bf16x8*)(Asb + m * 2048 + rA + u0);
            av[m][1] = *(const bf16x8*)(Asb + m * 2048 + rA + u1);
        }
        #pragma unroll
        for (int n = 0; n < 4; ++n) {
            bv[n][0] = *(const bf16x8*)(Bsb + w * 8192 + n * 2048 + rA + u0);
            bv[n][1] = *(const bf16x8*)(Bsb + w * 8192 + n * 2048 + rA + u1);
        }
        #pragma unroll
        for (int m = 0; m < 4; ++m)
            #pragma unroll
            for (int n = 0; n < 4; ++n) {
                acc[m][n] = __builtin_amdgcn_mfma_f32_16x16x32_bf16(av[m][0], bv[n][0], acc[m][n], 0, 0, 0);
                acc[m][n] = __builtin_amdgcn_mfma_f32_16x16x32_bf16(av[m][1], bv[n][1], acc[m][n], 0, 0, 0);
            }
        __syncthreads();
    }

    float scale = (nb == 0) ? 0.17677669529663689f : 1.0f;
    #pragma unroll
    for (int nf = 0; nf < 4; ++nf) {
        int o = w * 64 + nf * 16 + (lane & 15);
        float bias = qkv_b[nb * 256 + o];
        int hh = o >> 5, dd = o & 31;
        if (nb < 2) {
            _Float16* dstb = (nb == 0) ? qh : kh;
            _Float16* base = dstb + ((size_t)(gw * 8 + hh) * 64) * 32 + dd;
            #pragma unroll
            for (int mf = 0; mf < 4; ++mf) {
                int l0 = mf * 16 + (lane >> 4) * 4;
                #pragma unroll
                for (int j = 0; j < 4; ++j)
                    base[(size_t)(l0 + j) * 32] = (_Float16)((acc[mf][nf][j] + bias) * scale);
            }
        } else {
            _Float16* base = vt + ((size_t)(gw * 8 + hh) * 32 + dd) * 64;
            #pragma unroll
            for (int mf = 0; mf < 4; ++mf) {
                int l0 = mf * 16 + (lane >> 4) * 4;
                union { _Float16 x[4]; uint2 u; } pk;
                #pragma unroll
                for (int j = 0; j < 4; ++j) pk.x[j] = (_Float16)(acc[mf][nf][j] + bias);
                *(uint2*)(base + l0) = pk.u;
            }
        }
    }
}

// ---------------------------------------------------------------------------
// Attention via fp16 MFMA. Block = 1 window, 512 threads = 8 waves = 8 heads.
// ---------------------------------------------------------------------------
__global__ __launch_bounds__(512) void attn_mfma_kernel(
    const _Float16* __restrict__ qh, const _Float16* __restrict__ kh,
    const _Float16* __restrict__ vt, const float* __restrict__ rel_bias,
    unsigned short* __restrict__ attn_ob) {

    __shared__ __align__(16) char Plds[65536];   // 8 waves x 64 rows x 128B
    int n = blockIdx.x;
    int win = n & 63;
    int wy = win >> 3, wx = win & 7;
    int tid = threadIdx.x, lane = tid & 63, h = tid >> 6;
    int qc = lane & 15, g = lane >> 4;
    char* P = Plds + h * 8192;

    const _Float16* qp = qh + (size_t)(n * 8 + h) * 2048;
    const _Float16* kp = kh + (size_t)(n * 8 + h) * 2048;
    const _Float16* vp = vt + (size_t)(n * 8 + h) * 2048;
    const float* rb = rel_bias + (size_t)h * 4096;

    int rk[16];
    #pragma unroll
    for (int mt = 0; mt < 4; ++mt)
        #pragma unroll
        for (int j = 0; j < 4; ++j) {
            int key = mt * 16 + g * 4 + j;
            int rh = wy * 8 + (key >> 3), rw = wx * 8 + (key & 7);
            rk[mt * 4 + j] = (rh < 56 ? 0 : (rh < 60 ? 1 : 2)) * 3
                           + (rw < 56 ? 0 : (rw < 60 ? 1 : 2));
        }

    f16x8 kf[4];
    #pragma unroll
    for (int mt = 0; mt < 4; ++mt)
        kf[mt] = *(const f16x8*)(kp + (mt * 16 + qc) * 32 + g * 8);

    #pragma unroll
    for (int nt = 0; nt < 4; ++nt) {
        int q = nt * 16 + qc;
        int rqh = wy * 8 + (q >> 3), rqw = wx * 8 + (q & 7);
        int rq = (rqh < 56 ? 0 : (rqh < 60 ? 1 : 2)) * 3
               + (rqw < 56 ? 0 : (rqw < 60 ? 1 : 2));
        f16x8 qf = *(const f16x8*)(qp + q * 32 + g * 8);

        f32x4 s[4];
        #pragma unroll
        for (int mt = 0; mt < 4; ++mt) {
            f32x4 z = {0.0f, 0.0f, 0.0f, 0.0f};
            s[mt] = __builtin_amdgcn_mfma_f32_16x16x32_f16(kf[mt], qf, z, 0, 0, 0);
        }

        float vals[16];
        #pragma unroll
        for (int mt = 0; mt < 4; ++mt) {
            float4 bv4 = *(const float4*)(rb + q * 64 + mt * 16 + g * 4);
            vals[mt * 4 + 0] = s[mt][0] + bv4.x + (rk[mt * 4 + 0] != rq ? -100.0f : 0.0f);
            vals[mt * 4 + 1] = s[mt][1] + bv4.y + (rk[mt * 4 + 1] != rq ? -100.0f : 0.0f);
            vals[mt * 4 + 2] = s[mt][2] + bv4.z + (rk[mt * 4 + 2] != rq ? -100.0f : 0.0f);
            vals[mt * 4 + 3] = s[mt][3] + bv4.w + (rk[mt * 4 + 3] != rq ? -100.0f : 0.0f);
        }

        float mx = vals[0];
        #pragma unroll
        for (int i = 1; i < 16; ++i) mx = fmaxf(mx, vals[i]);
        mx = fmaxf(mx, __shfl_xor(mx, 16));
        mx = fmaxf(mx, __shfl_xor(mx, 32));

        float sum = 0.0f;
        #pragma unroll
        for (int i = 0; i < 16; ++i) { vals[i] = __expf(vals[i] - mx); sum += vals[i]; }
        sum += __shfl_xor(sum, 16);
        sum += __shfl_xor(sum, 32);
        float inv = 1.0f / sum;

        #pragma unroll
        for (int mt = 0; mt < 4; ++mt) {
            union { _Float16 x[4]; uint2 u; } pk4;
            #pragma unroll
            for (int j = 0; j < 4; ++j) pk4.x[j] = (_Float16)(vals[mt * 4 + j] * inv);
            int off = (mt * 32 + g * 8) ^ ((q & 7) << 4);
            *(uint2*)(P + q * 128 + off) = pk4.u;
        }
    }

    f16x8 pa[4][2];
    #pragma unroll
    for (int im = 0; im < 4; ++im)
        #pragma unroll
        for (int ks = 0; ks < 2; ++ks) {
            int row = im * 16 + qc;
            int off = (ks * 64 + g * 16) ^ ((row & 7) << 4);
            pa[im][ks] = *(const f16x8*)(P + row * 128 + off);
        }
    f16x8 bvv[2][2];
    #pragma unroll
    for (int in = 0; in < 2; ++in)
        #pragma unroll
        for (int ks = 0; ks < 2; ++ks)
            bvv[in][ks] = *(const f16x8*)(vp + (in * 16 + qc) * 64 + ks * 32 + g * 8);

    f32x4 acc[4][2];
    #pragma unroll
    for (int im = 0; im < 4; ++im)
        #pragma unroll
        for (int in = 0; in < 2; ++in) {
            f32x4 z = {0.0f, 0.0f, 0.0f, 0.0f};
            acc[im][in] = z;
        }
    #pragma unroll
    for (int im = 0; im < 4; ++im)
        #pragma unroll
        for (int in = 0; in < 2; ++in) {
            acc[im][in] = __builtin_amdgcn_mfma_f32_16x16x32_f16(pa[im][0], bvv[in][0], acc[im][in], 0, 0, 0);
            acc[im][in] = __builtin_amdgcn_mfma_f32_16x16x32_f16(pa[im][1], bvv[in][1], acc[im][in], 0, 0, 0);
        }

    #pragma unroll
    for (int im = 0; im < 4; ++im)
        #pragma unroll
        for (int in = 0; in < 2; ++in)
            #pragma unroll
            for (int j = 0; j < 4; ++j) {
                int q2 = im * 16 + g * 4 + j;
                attn_ob[(size_t)(n * 64 + q2) * 256 + h * 32 + in * 16 + qc] =
                    pack1_bf16(acc[im][in][j]);
            }
}

// ---------------------------------------------------------------------------
// Proj GEMM via bf16 MFMA. Block = 64 M x 256 N. grid 512. fp16 feat output.
// ---------------------------------------------------------------------------
__global__ __launch_bounds__(256) void proj_mfma_kernel(
    const unsigned short* __restrict__ attn_ob, const unsigned short* __restrict__ pwb,
    const float* __restrict__ proj_b, _Float16* __restrict__ feath) {

    __shared__ __align__(16) char Asb[8192];
    __shared__ __align__(16) char Bsb[32768];

    int m0 = blockIdx.x * 64;
    int tid = threadIdx.x;
    int lane = tid & 63, w = tid >> 6;
    int gw = m0 >> 6;
    int bidx = gw >> 6, win = gw & 63;

    f32x4 acc[4][4];
    #pragma unroll
    for (int m = 0; m < 4; ++m)
        #pragma unroll
        for (int n = 0; n < 4; ++n) {
            f32x4 z = {0.0f, 0.0f, 0.0f, 0.0f};
            acc[m][n] = z;
        }

    const char* ac = (const char*)attn_ob;
    const char* wc = (const char*)pwb;
    int rA = (lane & 15) * 128;
    int u0 = (((lane >> 4)    ) ^ (lane & 7)) << 4;
    int u1 = ((4 + (lane >> 4)) ^ (lane & 7)) << 4;

    for (int c = 0; c < 4; ++c) {
        #pragma unroll
        for (int r = 0; r < 2; ++r) {
            int pos = r * 256 + tid;
            int row = pos >> 3, u = pos & 7;
            const char* src = ac + (size_t)(m0 + row) * 512 + c * 128 + ((u ^ (row & 7)) << 4);
            __builtin_amdgcn_global_load_lds(
                (const __attribute__((address_space(1))) unsigned int*)src,
                (__attribute__((address_space(3))) unsigned int*)(Asb + pos * 16),
                16, 0, 0);
        }
        #pragma unroll
        for (int r = 0; r < 8; ++r) {
            int pos = r * 256 + tid;
            int n = pos >> 3, u = pos & 7;
            const char* src = wc + (size_t)n * 512 + c * 128 + ((u ^ (n & 7)) << 4);
            __builtin_amdgcn_global_load_lds(
                (const __attribute__((address_space(1))) unsigned int*)src,
                (__attribute__((address_space(3))) unsigned int*)(Bsb + pos * 16),
                16, 0, 0);
        }
        __syncthreads();

        bf16x8 av[4][2], bv[4][2];
        #pragma unroll
        for (int m = 0; m < 4; ++m) {
            av[m][0] = *(const bf16x8*)(Asb + m * 2048 + rA + u0);
            av[m][1] = *(const bf16x8*)(Asb + m * 2048 + rA + u1);
        }
        #pragma unroll
        for (int n = 0; n < 4; ++n) {
            bv[n][0] = *(const bf16x8*)(Bsb + w * 8192 + n * 2048 + rA + u0);
            bv[n][1] = *(const bf16x8*)(Bsb + w * 8192 + n * 2048 + rA + u1);
        }
        #pragma unroll
        for (int m = 0; m < 4; ++m)
            #pragma unroll
            for (int n = 0; n < 4; ++n) {
                acc[m][n] = __builtin_amdgcn_mfma_f32_16x16x32_bf16(av[m][0], bv[n][0], acc[m][n], 0, 0, 0);
                acc[m][n] = __builtin_amdgcn_mfma_f32_16x16x32_bf16(av[m][1], bv[n][1], acc[m][n], 0, 0, 0);
            }
        __syncthreads();
    }

    #pragma unroll
    for (int nf = 0; nf < 4; ++nf) {
        int f = w * 64 + nf * 16 + (lane & 15);
        float bias = proj_b[f];
        #pragma unroll
        for (int mf = 0; mf < 4; ++mf) {
            #pragma unroll
            for (int j = 0; j < 4; ++j) {
                int px = mf * 16 + (lane >> 4) * 4 + j;
                int rh = ((win >> 3) << 3) + (px >> 3);
                int rw = ((win & 7) << 3) + (px & 7);
                int p = (rh + 4) & 63;
                int qq = (rw + 4) & 63;
                feath[((size_t)(bidx * 64 + p) * 64 + qq) * 256 + f] =
                    (_Float16)(acc[mf][nf][j] + bias);
            }
        }
    }
}

// ---------------------------------------------------------------------------
// Fused bilinear-sample + conv, f16 MFMA implicit GEMM, v2:
//  - B (weights) loaded direct global->VGPR fragments (wT2h L2-resident)
//  - A (samples) double-buffered 8KB LDS, T14 split: loads early, write late
//  - XCD-aware decode: b = blk&7 so each batch's feat stays in one XCD L2
// ---------------------------------------------------------------------------
__global__ __launch_bounds__(256) void sample_conv_mfma2_kernel(
    const _Float16* __restrict__ feath, const float* __restrict__ ymap,
    const _Float16* __restrict__ wT2h, const float* __restrict__ dsc_b,
    float* __restrict__ out) {

    __shared__ __align__(16) char Asb[2][8192];   // [buf][64 px * 128B]
    __shared__ unsigned row0[9][64];
    __shared__ unsigned row1[9][64];
    __shared__ float    wyv[9][64];

    int blk = blockIdx.x;              // 0..511; XCD swizzle: b = blk&7
    int b = blk & 7, wd = blk >> 3;
    int tid = threadIdx.x;
    int lane = tid & 63, w = tid >> 6;
    int qc = lane & 15, g = lane >> 4;

    for (int idx = tid; idx < 576; idx += 256) {
        int k = idx >> 6, hd = idx & 63;
        float y = ymap[((size_t)(b * 576 + wd * 9 + k)) * 64 + hd];
        y = fminf(fmaxf(y, 0.0f), 63.0f);
        float y0f = floorf(y);
        int y0 = (int)y0f;
        int y1 = min(y0 + 1, 63);
        int xc = min(max(hd + k - 4, 0), 63);
        row0[k][hd] = (unsigned)(((b * 64 + y0) * 64 + xc) * 512);
        row1[k][hd] = (unsigned)(((b * 64 + y1) * 64 + xc) * 512);
        wyv[k][hd] = y - y0f;
    }

    f32x4 acc[4][4];
    #pragma unroll
    for (int m = 0; m < 4; ++m)
        #pragma unroll
        for (int n = 0; n < 4; ++n) {
            f32x4 z = {0.0f, 0.0f, 0.0f, 0.0f};
            acc[m][n] = z;
        }

    const char* featc = (const char*)feath;
    const char* wc    = (const char*)wT2h;

    int pxA0 = tid >> 3;   // A-stage pixel (r=0)
    int sA   = tid & 7;    // A-stage 16B slot
    int rA = qc * 128;
    int u0 = ((g    ) ^ (lane & 7)) << 4;
    int u1 = ((4 + g) ^ (lane & 7)) << 4;

    // B fragment row bases: oc(n) = w*64 + n*16 + qc
    const char* wrow[4];
    #pragma unroll
    for (int n = 0; n < 4; ++n)
        wrow[n] = wc + (size_t)(w * 64 + n * 16 + qc) * 4608 + g * 16;

    // staging registers (T14 split)
    f16x8 s0[2], s1[2];
    float swy[2];

    __syncthreads();   // tables ready

    // prologue: stage c=0 into buf 0
    {
        int ks = 0, cib = 0;
        #pragma unroll
        for (int r = 0; r < 2; ++r) {
            int px = pxA0 + r * 32;
            unsigned b0 = row0[ks][px] + cib + sA * 16;
            unsigned b1 = row1[ks][px] + cib + sA * 16;
            swy[r] = wyv[ks][px];
            s0[r] = *(const f16x8*)(featc + b0);
            s1[r] = *(const f16x8*)(featc + b1);
        }
        #pragma unroll
        for (int r = 0; r < 2; ++r) {
            int px = pxA0 + r * 32;
            _Float16 wyh = (_Float16)swy[r];
            _Float16 omh = (_Float16)(1.0f - swy[r]);
            f16x8 res = s0[r] * omh + s1[r] * wyh;
            *(f16x8*)(Asb[0] + px * 128 + ((sA ^ (px & 7)) << 4)) = res;
        }
    }
    __syncthreads();

    for (int c = 0; c < 36; ++c) {
        int cur = c & 1;

        // B fragments: direct global (L2-resident weights)
        f16x8 bv[4][2];
        #pragma unroll
        for (int n = 0; n < 4; ++n) {
            bv[n][0] = *(const f16x8*)(wrow[n] + c * 128);
            bv[n][1] = *(const f16x8*)(wrow[n] + c * 128 + 64);
        }

        // issue next tile's feat loads early (latency hides under MFMA)
        if (c < 35) {
            int cn = c + 1;
            int ks = cn >> 2, cib = (cn & 3) * 128;
            #pragma unroll
            for (int r = 0; r < 2; ++r) {
                int px = pxA0 + r * 32;
                unsigned b0 = row0[ks][px] + cib + sA * 16;
                unsigned b1 = row1[ks][px] + cib + sA * 16;
                swy[r] = wyv[ks][px];
                s0[r] = *(const f16x8*)(featc + b0);
                s1[r] = *(const f16x8*)(featc + b1);
            }
        }

        // A fragments from current buffer
        f16x8 av[4][2];
        #pragma unroll
        for (int m = 0; m < 4; ++m) {
            av[m][0] = *(const f16x8*)(Asb[cur] + m * 2048 + rA + u0);
            av[m][1] = *(const f16x8*)(Asb[cur] + m * 2048 + rA + u1);
        }

        #pragma unroll
        for (int m = 0; m < 4; ++m)
            #pragma unroll
            for (int n = 0; n < 4; ++n) {
                acc[m][n] = __builtin_amdgcn_mfma_f32_16x16x32_f16(av[m][0], bv[n][0], acc[m][n], 0, 0, 0);
                acc[m][n] = __builtin_amdgcn_mfma_f32_16x16x32_f16(av[m][1], bv[n][1], acc[m][n], 0, 0, 0);
            }

        // write next tile into the other buffer
        if (c < 35) {
            #pragma unroll
            for (int r = 0; r < 2; ++r) {
                int px = pxA0 + r * 32;
                _Float16 wyh = (_Float16)swy[r];
                _Float16 omh = (_Float16)(1.0f - swy[r]);
                f16x8 res = s0[r] * omh + s1[r] * wyh;
                *(f16x8*)(Asb[cur ^ 1] + px * 128 + ((sA ^ (px & 7)) << 4)) = res;
            }
        }
        __syncthreads();
    }

    #pragma unroll
    for (int n = 0; n < 4; ++n) {
        int o = w * 64 + n * 16 + qc;
        float bvs = dsc_b[o];
        float* orow = out + ((size_t)(b * 256 + o) * 64 + wd) * 64;
        #pragma unroll
        for (int m = 0; m < 4; ++m) {
            int px = m * 16 + g * 4;
            float4 res;
            res.x = fmaxf(acc[m][n][0] + bvs, 0.0f);
            res.y = fmaxf(acc[m][n][1] + bvs, 0.0f);
            res.z = fmaxf(acc[m][n][2] + bvs, 0.0f);
            res.w = fmaxf(acc[m][n][3] + bvs, 0.0f);
            *(float4*)(orow + px) = res;
        }
    }
}

// ---------------------------------------------------------------------------
extern "C" void kernel_launch(void* const* d_in, const int* in_sizes, int n_in,
                              void* d_out, int out_size, void* d_ws, size_t ws_size,
                              hipStream_t stream) {
    (void)in_sizes; (void)n_in; (void)out_size; (void)ws_size;
    const float* x        = (const float*)d_in[0];
    const float* qkv_w    = (const float*)d_in[1];
    const float* qkv_b    = (const float*)d_in[2];
    const float* proj_w   = (const float*)d_in[3];
    const float* proj_b   = (const float*)d_in[4];
    const float* rel_bias = (const float*)d_in[5];
    const float* offset   = (const float*)d_in[6];
    const float* dsc_w    = (const float*)d_in[7];
    const float* dsc_b    = (const float*)d_in[8];
    float* out = (float*)d_out;

    unsigned short* wsu = (unsigned short*)d_ws;
    _Float16* qh = (_Float16*)wsu;                                  // 8.39M fp16
    _Float16* kh = (_Float16*)(wsu + NFLOAT_BUF);
    _Float16* vt = (_Float16*)(wsu + 2 * (size_t)NFLOAT_BUF);
    unsigned short* attn_ob = wsu + 3 * (size_t)NFLOAT_BUF;         // bf16
    _Float16* feath = (_Float16*)(wsu + 4 * (size_t)NFLOAT_BUF);    // fp16
    unsigned short* xb      = wsu + 5 * (size_t)NFLOAT_BUF;         // bf16
    unsigned short* wb      = wsu + 6 * (size_t)NFLOAT_BUF;         // 196608 bf16
    unsigned short* pwb     = wb + 196608;                          // 65536 bf16
    _Float16* wT2h          = (_Float16*)(pwb + 65536);             // 589824 fp16
    float* ymap = (float*)((unsigned short*)wT2h + 589824);         // 294912 f32

    cvt_bf16_kernel<<<4096, 256, 0, stream>>>(x, xb, 1048576);
    cvt_bf16_kernel<<<96, 256, 0, stream>>>(qkv_w, wb, 24576);
    cvt_bf16_kernel<<<32, 256, 0, stream>>>(proj_w, pwb, 8192);
    transpose_w_kernel<<<2304, 256, 0, stream>>>(dsc_w, wT2h);
    ymap_kernel<<<128, 256, 0, stream>>>(offset, ymap);
    qkv_mfma_kernel<<<dim3(3, 512), 256, 0, stream>>>(xb, wb, qkv_b, qh, kh, vt);
    attn_mfma_kernel<<<512, 512, 0, stream>>>(qh, kh, vt, rel_bias, attn_ob);
    proj_mfma_kernel<<<512, 256, 0, stream>>>(attn_ob, pwb, proj_b, feath);
    sample_conv_mfma2_kernel<<<512, 256, 0, stream>>>(feath, ymap, wT2h, dsc_b, out);
}

// Round 7
// 227.395 us; speedup vs baseline: 1.1063x; 1.1063x over previous
//
#include <hip/hip_runtime.h>
#include <math.h>

// Shapes: B=8, H=W=64, C=256, HEADS=8, d=32, WS=8, SS=4, K=9
// NTOK = 32768 tokens; 512 windows of 64 tokens.
// Conv = implicit GEMM: M=32768 px, N=256 oc, K=2304 (f16 MFMA, B via gload_lds).
// QKV  = GEMM M=32768, N=768, K=256 (bf16 MFMA, fp16 outputs).
// Attn = per-window MFMA fp16: S^T = K·Q^T, O = P·V^T. 1 wave = 1 head.
// Proj = GEMM M=32768, N=256, K=256 (bf16 MFMA, fp16 feat output).

#define NFLOAT_BUF 8388608  // 32768*256

typedef float f32x4 __attribute__((ext_vector_type(4)));
typedef __bf16 bf16x8 __attribute__((ext_vector_type(8)));
typedef _Float16 f16x8 __attribute__((ext_vector_type(8)));

__device__ inline unsigned pack2_bf16(float a, float b) {
    union { float f; unsigned u; } ua, ub;
    ua.f = a; ub.f = b;
    unsigned ra = (ua.u + 0x7FFFu + ((ua.u >> 16) & 1u)) >> 16;
    unsigned rb = (ub.u + 0x7FFFu + ((ub.u >> 16) & 1u)) & 0xFFFF0000u;
    return (ra & 0xFFFFu) | rb;
}
__device__ inline unsigned short pack1_bf16(float a) {
    union { float f; unsigned u; } v;
    v.f = a;
    return (unsigned short)((v.u + 0x7FFFu + ((v.u >> 16) & 1u)) >> 16);
}

// ---------------------------------------------------------------------------
// fp32 -> bf16 bulk convert (8 elems/thread)
// ---------------------------------------------------------------------------
__global__ __launch_bounds__(256) void cvt_bf16_kernel(const float* __restrict__ src,
                                                       unsigned short* __restrict__ dst,
                                                       int n8) {
    int t = blockIdx.x * 256 + threadIdx.x;
    if (t >= n8) return;
    const float4* s = (const float4*)(src + (size_t)t * 8);
    float4 a = s[0], b = s[1];
    uint4 o;
    o.x = pack2_bf16(a.x, a.y); o.y = pack2_bf16(a.z, a.w);
    o.z = pack2_bf16(b.x, b.y); o.w = pack2_bf16(b.z, b.w);
    *(uint4*)(dst + (size_t)t * 8) = o;
}

// ---------------------------------------------------------------------------
// dsc_weight (O=256, I=256, K=9) -> wT2h fp16 [o][kk=k*256+i]
// ---------------------------------------------------------------------------
__global__ __launch_bounds__(256) void transpose_w_kernel(const float* __restrict__ w,
                                                          _Float16* __restrict__ wT) {
    int t = blockIdx.x * 256 + threadIdx.x;   // < 589824
    int o = t / 2304;
    int kk = t - o * 2304;
    int k = kk >> 8, i = kk & 255;
    wT[t] = (_Float16)w[(o * 256 + i) * 9 + k];
}

// ---------------------------------------------------------------------------
// snake coordinate map -> ymap[b][wd*9+k][hd]
// ---------------------------------------------------------------------------
__global__ __launch_bounds__(256) void ymap_kernel(const float* __restrict__ offset,
                                                   float* __restrict__ ymap) {
    int t = blockIdx.x * 256 + threadIdx.x;   // < 32768
    int hd = t & 63;
    int wd = (t >> 6) & 63;
    int b  = t >> 12;
    const float* op = offset + ((size_t)(b * 18) * 64 + wd) * 64 + hd;
    float yo[9];
    #pragma unroll
    for (int k = 0; k < 9; ++k) yo[k] = op[(size_t)k * 4096];
    float cum[9];
    cum[4] = 0.0f;
    float s = 0.0f;
    for (int j = 3; j >= 0; --j) { s += yo[j]; cum[j] = s; }
    s = 0.0f;
    for (int j = 5; j < 9; ++j) { s += yo[j]; cum[j] = s; }
    float wdf = (float)wd;
    float* yp = ymap + ((size_t)(b * 576 + wd * 9)) * 64 + hd;
    #pragma unroll
    for (int k = 0; k < 9; ++k) yp[(size_t)k * 64] = wdf + cum[k];
}

// ---------------------------------------------------------------------------
// QKV GEMM via bf16 MFMA. Block = 64 M-rows x 256 N. grid (3, 512).
// Outputs fp16: q,k as [win*8+h][l][32]; v transposed [win*8+h][32][64].
// ---------------------------------------------------------------------------
__global__ __launch_bounds__(256) void qkv_mfma_kernel(
    const unsigned short* __restrict__ xb, const unsigned short* __restrict__ wb,
    const float* __restrict__ qkv_b,
    _Float16* __restrict__ qh, _Float16* __restrict__ kh, _Float16* __restrict__ vt) {

    __shared__ __align__(16) char Asb[8192];    // 64 rows * 128B
    __shared__ __align__(16) char Bsb[32768];   // 256 rows * 128B
    __shared__ unsigned rowoff[64];

    int nb = blockIdx.x;          // 0..2  (q / k / v)
    int m0 = blockIdx.y * 64;
    int tid = threadIdx.x;
    int lane = tid & 63, w = tid >> 6;
    int gw = m0 >> 6;             // global window

    if (tid < 64) {
        int l = tid;
        int b = gw >> 6, win = gw & 63;
        int rh = ((win >> 3) << 3) + (l >> 3);
        int rw = ((win & 7) << 3) + (l & 7);
        int sh = (rh + 4) & 63, sw = (rw + 4) & 63;
        rowoff[l] = (unsigned)(((b * 64 + sh) * 64 + sw) * 512);  // byte offset
    }

    f32x4 acc[4][4];
    #pragma unroll
    for (int m = 0; m < 4; ++m)
        #pragma unroll
        for (int n = 0; n < 4; ++n) {
            f32x4 z = {0.0f, 0.0f, 0.0f, 0.0f};
            acc[m][n] = z;
        }

    const char* xc = (const char*)xb;
    const char* wc = (const char*)wb;
    int rA = (lane & 15) * 128;
    int u0 = (((lane >> 4)    ) ^ (lane & 7)) << 4;
    int u1 = ((4 + (lane >> 4)) ^ (lane & 7)) << 4;

    __syncthreads();

    for (int c = 0; c < 4; ++c) {   // K chunks of 64
        #pragma unroll
        for (int r = 0; r < 2; ++r) {
            int pos = r * 256 + tid;
            int row = pos >> 3, u = pos & 7;
            const char* src = xc + rowoff[row] + c * 128 + ((u ^ (row & 7)) << 4);
            __builtin_amdgcn_global_load_lds(
                (const __attribute__((address_space(1))) unsigned int*)src,
                (__attribute__((address_space(3))) unsigned int*)(Asb + pos * 16),
                16, 0, 0);
        }
        #pragma unroll
        for (int r = 0; r < 8; ++r) {
            int pos = r * 256 + tid;
            int n = pos >> 3, u = pos & 7;
            const char* src = wc + (size_t)(nb * 256 + n) * 512 + c * 128 + ((u ^ (n & 7)) << 4);
            __builtin_amdgcn_global_load_lds(
                (const __attribute__((address_space(1))) unsigned int*)src,
                (__attribute__((address_space(3))) unsigned int*)(Bsb + pos * 16),
                16, 0, 0);
        }
        __syncthreads();

        bf16x8 av[4][2], bv[4][2];
        #pragma unroll
        for (int m = 0; m < 4; ++m) {
            av[m][0] = *(const bf16x8*)(Asb + m * 2048 + rA + u0);
            av[m][1] = *(const bf16x8*)(Asb + m * 2048 + rA + u1);
        }
        #pragma unroll
        for (int n = 0; n < 4; ++n) {
            bv[n][0] = *(const bf16x8*)(Bsb + w * 8192 + n * 2048 + rA + u0);
            bv[n][1] = *(const bf16x8*)(Bsb + w * 8192 + n * 2048 + rA + u1);
        }
        #pragma unroll
        for (int m = 0; m < 4; ++m)
            #pragma unroll
            for (int n = 0; n < 4; ++n) {
                acc[m][n] = __builtin_amdgcn_mfma_f32_16x16x32_bf16(av[m][0], bv[n][0], acc[m][n], 0, 0, 0);
                acc[m][n] = __builtin_amdgcn_mfma_f32_16x16x32_bf16(av[m][1], bv[n][1], acc[m][n], 0, 0, 0);
            }
        __syncthreads();
    }

    float scale = (nb == 0) ? 0.17677669529663689f : 1.0f;
    #pragma unroll
    for (int nf = 0; nf < 4; ++nf) {
        int o = w * 64 + nf * 16 + (lane & 15);
        float bias = qkv_b[nb * 256 + o];
        int hh = o >> 5, dd = o & 31;
        if (nb < 2) {
            _Float16* dstb = (nb == 0) ? qh : kh;
            _Float16* base = dstb + ((size_t)(gw * 8 + hh) * 64) * 32 + dd;
            #pragma unroll
            for (int mf = 0; mf < 4; ++mf) {
                int l0 = mf * 16 + (lane >> 4) * 4;
                #pragma unroll
                for (int j = 0; j < 4; ++j)
                    base[(size_t)(l0 + j) * 32] = (_Float16)((acc[mf][nf][j] + bias) * scale);
            }
        } else {
            _Float16* base = vt + ((size_t)(gw * 8 + hh) * 32 + dd) * 64;
            #pragma unroll
            for (int mf = 0; mf < 4; ++mf) {
                int l0 = mf * 16 + (lane >> 4) * 4;
                union { _Float16 x[4]; uint2 u; } pk;
                #pragma unroll
                for (int j = 0; j < 4; ++j) pk.x[j] = (_Float16)(acc[mf][nf][j] + bias);
                *(uint2*)(base + l0) = pk.u;
            }
        }
    }
}

// ---------------------------------------------------------------------------
// Attention via fp16 MFMA. Block = 1 window, 512 threads = 8 waves = 8 heads.
// ---------------------------------------------------------------------------
__global__ __launch_bounds__(512) void attn_mfma_kernel(
    const _Float16* __restrict__ qh, const _Float16* __restrict__ kh,
    const _Float16* __restrict__ vt, const float* __restrict__ rel_bias,
    unsigned short* __restrict__ attn_ob) {

    __shared__ __align__(16) char Plds[65536];   // 8 waves x 64 rows x 128B
    int n = blockIdx.x;
    int win = n & 63;
    int wy = win >> 3, wx = win & 7;
    int tid = threadIdx.x, lane = tid & 63, h = tid >> 6;
    int qc = lane & 15, g = lane >> 4;
    char* P = Plds + h * 8192;

    const _Float16* qp = qh + (size_t)(n * 8 + h) * 2048;
    const _Float16* kp = kh + (size_t)(n * 8 + h) * 2048;
    const _Float16* vp = vt + (size_t)(n * 8 + h) * 2048;
    const float* rb = rel_bias + (size_t)h * 4096;

    int rk[16];
    #pragma unroll
    for (int mt = 0; mt < 4; ++mt)
        #pragma unroll
        for (int j = 0; j < 4; ++j) {
            int key = mt * 16 + g * 4 + j;
            int rh = wy * 8 + (key >> 3), rw = wx * 8 + (key & 7);
            rk[mt * 4 + j] = (rh < 56 ? 0 : (rh < 60 ? 1 : 2)) * 3
                           + (rw < 56 ? 0 : (rw < 60 ? 1 : 2));
        }

    f16x8 kf[4];
    #pragma unroll
    for (int mt = 0; mt < 4; ++mt)
        kf[mt] = *(const f16x8*)(kp + (mt * 16 + qc) * 32 + g * 8);

    #pragma unroll
    for (int nt = 0; nt < 4; ++nt) {
        int q = nt * 16 + qc;
        int rqh = wy * 8 + (q >> 3), rqw = wx * 8 + (q & 7);
        int rq = (rqh < 56 ? 0 : (rqh < 60 ? 1 : 2)) * 3
               + (rqw < 56 ? 0 : (rqw < 60 ? 1 : 2));
        f16x8 qf = *(const f16x8*)(qp + q * 32 + g * 8);

        f32x4 s[4];
        #pragma unroll
        for (int mt = 0; mt < 4; ++mt) {
            f32x4 z = {0.0f, 0.0f, 0.0f, 0.0f};
            s[mt] = __builtin_amdgcn_mfma_f32_16x16x32_f16(kf[mt], qf, z, 0, 0, 0);
        }

        float vals[16];
        #pragma unroll
        for (int mt = 0; mt < 4; ++mt) {
            float4 bv4 = *(const float4*)(rb + q * 64 + mt * 16 + g * 4);
            vals[mt * 4 + 0] = s[mt][0] + bv4.x + (rk[mt * 4 + 0] != rq ? -100.0f : 0.0f);
            vals[mt * 4 + 1] = s[mt][1] + bv4.y + (rk[mt * 4 + 1] != rq ? -100.0f : 0.0f);
            vals[mt * 4 + 2] = s[mt][2] + bv4.z + (rk[mt * 4 + 2] != rq ? -100.0f : 0.0f);
            vals[mt * 4 + 3] = s[mt][3] + bv4.w + (rk[mt * 4 + 3] != rq ? -100.0f : 0.0f);
        }

        float mx = vals[0];
        #pragma unroll
        for (int i = 1; i < 16; ++i) mx = fmaxf(mx, vals[i]);
        mx = fmaxf(mx, __shfl_xor(mx, 16));
        mx = fmaxf(mx, __shfl_xor(mx, 32));

        float sum = 0.0f;
        #pragma unroll
        for (int i = 0; i < 16; ++i) { vals[i] = __expf(vals[i] - mx); sum += vals[i]; }
        sum += __shfl_xor(sum, 16);
        sum += __shfl_xor(sum, 32);
        float inv = 1.0f / sum;

        #pragma unroll
        for (int mt = 0; mt < 4; ++mt) {
            union { _Float16 x[4]; uint2 u; } pk4;
            #pragma unroll
            for (int j = 0; j < 4; ++j) pk4.x[j] = (_Float16)(vals[mt * 4 + j] * inv);
            int off = (mt * 32 + g * 8) ^ ((q & 7) << 4);
            *(uint2*)(P + q * 128 + off) = pk4.u;
        }
    }

    f16x8 pa[4][2];
    #pragma unroll
    for (int im = 0; im < 4; ++im)
        #pragma unroll
        for (int ks = 0; ks < 2; ++ks) {
            int row = im * 16 + qc;
            int off = (ks * 64 + g * 16) ^ ((row & 7) << 4);
            pa[im][ks] = *(const f16x8*)(P + row * 128 + off);
        }
    f16x8 bvv[2][2];
    #pragma unroll
    for (int in = 0; in < 2; ++in)
        #pragma unroll
        for (int ks = 0; ks < 2; ++ks)
            bvv[in][ks] = *(const f16x8*)(vp + (in * 16 + qc) * 64 + ks * 32 + g * 8);

    f32x4 acc[4][2];
    #pragma unroll
    for (int im = 0; im < 4; ++im)
        #pragma unroll
        for (int in = 0; in < 2; ++in) {
            f32x4 z = {0.0f, 0.0f, 0.0f, 0.0f};
            acc[im][in] = z;
        }
    #pragma unroll
    for (int im = 0; im < 4; ++im)
        #pragma unroll
        for (int in = 0; in < 2; ++in) {
            acc[im][in] = __builtin_amdgcn_mfma_f32_16x16x32_f16(pa[im][0], bvv[in][0], acc[im][in], 0, 0, 0);
            acc[im][in] = __builtin_amdgcn_mfma_f32_16x16x32_f16(pa[im][1], bvv[in][1], acc[im][in], 0, 0, 0);
        }

    #pragma unroll
    for (int im = 0; im < 4; ++im)
        #pragma unroll
        for (int in = 0; in < 2; ++in)
            #pragma unroll
            for (int j = 0; j < 4; ++j) {
                int q2 = im * 16 + g * 4 + j;
                attn_ob[(size_t)(n * 64 + q2) * 256 + h * 32 + in * 16 + qc] =
                    pack1_bf16(acc[im][in][j]);
            }
}

// ---------------------------------------------------------------------------
// Proj GEMM via bf16 MFMA. Block = 64 M x 256 N. grid 512. fp16 feat output.
// ---------------------------------------------------------------------------
__global__ __launch_bounds__(256) void proj_mfma_kernel(
    const unsigned short* __restrict__ attn_ob, const unsigned short* __restrict__ pwb,
    const float* __restrict__ proj_b, _Float16* __restrict__ feath) {

    __shared__ __align__(16) char Asb[8192];
    __shared__ __align__(16) char Bsb[32768];

    int m0 = blockIdx.x * 64;
    int tid = threadIdx.x;
    int lane = tid & 63, w = tid >> 6;
    int gw = m0 >> 6;
    int bidx = gw >> 6, win = gw & 63;

    f32x4 acc[4][4];
    #pragma unroll
    for (int m = 0; m < 4; ++m)
        #pragma unroll
        for (int n = 0; n < 4; ++n) {
            f32x4 z = {0.0f, 0.0f, 0.0f, 0.0f};
            acc[m][n] = z;
        }

    const char* ac = (const char*)attn_ob;
    const char* wc = (const char*)pwb;
    int rA = (lane & 15) * 128;
    int u0 = (((lane >> 4)    ) ^ (lane & 7)) << 4;
    int u1 = ((4 + (lane >> 4)) ^ (lane & 7)) << 4;

    for (int c = 0; c < 4; ++c) {
        #pragma unroll
        for (int r = 0; r < 2; ++r) {
            int pos = r * 256 + tid;
            int row = pos >> 3, u = pos & 7;
            const char* src = ac + (size_t)(m0 + row) * 512 + c * 128 + ((u ^ (row & 7)) << 4);
            __builtin_amdgcn_global_load_lds(
                (const __attribute__((address_space(1))) unsigned int*)src,
                (__attribute__((address_space(3))) unsigned int*)(Asb + pos * 16),
                16, 0, 0);
        }
        #pragma unroll
        for (int r = 0; r < 8; ++r) {
            int pos = r * 256 + tid;
            int n = pos >> 3, u = pos & 7;
            const char* src = wc + (size_t)n * 512 + c * 128 + ((u ^ (n & 7)) << 4);
            __builtin_amdgcn_global_load_lds(
                (const __attribute__((address_space(1))) unsigned int*)src,
                (__attribute__((address_space(3))) unsigned int*)(Bsb + pos * 16),
                16, 0, 0);
        }
        __syncthreads();

        bf16x8 av[4][2], bv[4][2];
        #pragma unroll
        for (int m = 0; m < 4; ++m) {
            av[m][0] = *(const bf16x8*)(Asb + m * 2048 + rA + u0);
            av[m][1] = *(const bf16x8*)(Asb + m * 2048 + rA + u1);
        }
        #pragma unroll
        for (int n = 0; n < 4; ++n) {
            bv[n][0] = *(const bf16x8*)(Bsb + w * 8192 + n * 2048 + rA + u0);
            bv[n][1] = *(const bf16x8*)(Bsb + w * 8192 + n * 2048 + rA + u1);
        }
        #pragma unroll
        for (int m = 0; m < 4; ++m)
            #pragma unroll
            for (int n = 0; n < 4; ++n) {
                acc[m][n] = __builtin_amdgcn_mfma_f32_16x16x32_bf16(av[m][0], bv[n][0], acc[m][n], 0, 0, 0);
                acc[m][n] = __builtin_amdgcn_mfma_f32_16x16x32_bf16(av[m][1], bv[n][1], acc[m][n], 0, 0, 0);
            }
        __syncthreads();
    }

    #pragma unroll
    for (int nf = 0; nf < 4; ++nf) {
        int f = w * 64 + nf * 16 + (lane & 15);
        float bias = proj_b[f];
        #pragma unroll
        for (int mf = 0; mf < 4; ++mf) {
            #pragma unroll
            for (int j = 0; j < 4; ++j) {
                int px = mf * 16 + (lane >> 4) * 4 + j;
                int rh = ((win >> 3) << 3) + (px >> 3);
                int rw = ((win & 7) << 3) + (px & 7);
                int p = (rh + 4) & 63;
                int qq = (rw + 4) & 63;
                feath[((size_t)(bidx * 64 + p) * 64 + qq) * 256 + f] =
                    (_Float16)(acc[mf][nf][j] + bias);
            }
        }
    }
}

// ---------------------------------------------------------------------------
// Fused bilinear-sample + conv, f16 MFMA implicit GEMM, v3:
//  - B staged via global_load_lds (coalesced; v1-proven structure)
//  - A staged with fp16 v_pk_fma lerp (v2-proven VALU cut)
//  - XCD-aware decode b = blk&7 (v2-proven traffic cut: feat slice in one L2)
// ---------------------------------------------------------------------------
__global__ __launch_bounds__(256) void sample_conv_mfma3_kernel(
    const _Float16* __restrict__ feath, const float* __restrict__ ymap,
    const _Float16* __restrict__ wT2h, const float* __restrict__ dsc_b,
    float* __restrict__ out) {

    __shared__ __align__(16) char Asb[8192];    // 64 px * 128B (64 ch fp16)
    __shared__ __align__(16) char Bsb[32768];   // 256 oc * 128B
    __shared__ unsigned row0[9][64];
    __shared__ unsigned row1[9][64];
    __shared__ float    wyv[9][64];

    int blk = blockIdx.x;              // 0..511; XCD swizzle
    int b = blk & 7, wd = blk >> 3;
    int tid = threadIdx.x;
    int lane = tid & 63, w = tid >> 6;
    int qc = lane & 15, g = lane >> 4;

    for (int idx = tid; idx < 576; idx += 256) {
        int k = idx >> 6, hd = idx & 63;
        float y = ymap[((size_t)(b * 576 + wd * 9 + k)) * 64 + hd];
        y = fminf(fmaxf(y, 0.0f), 63.0f);
        float y0f = floorf(y);
        int y0 = (int)y0f;
        int y1 = min(y0 + 1, 63);
        int xc = min(max(hd + k - 4, 0), 63);
        row0[k][hd] = (unsigned)(((b * 64 + y0) * 64 + xc) * 512);  // byte offset (256ch fp16)
        row1[k][hd] = (unsigned)(((b * 64 + y1) * 64 + xc) * 512);
        wyv[k][hd] = y - y0f;
    }

    f32x4 acc[4][4];
    #pragma unroll
    for (int m = 0; m < 4; ++m)
        #pragma unroll
        for (int n = 0; n < 4; ++n) {
            f32x4 z = {0.0f, 0.0f, 0.0f, 0.0f};
            acc[m][n] = z;
        }

    const char* featc = (const char*)feath;
    const char* wc    = (const char*)wT2h;

    int pxA0 = tid >> 3;   // A-stage pixel (r=0)
    int sA   = tid & 7;    // A-stage 16B slot
    int rA = qc * 128;
    int u0 = ((g    ) ^ (lane & 7)) << 4;
    int u1 = ((4 + g) ^ (lane & 7)) << 4;

    __syncthreads();   // tables ready

    for (int c = 0; c < 36; ++c) {
        // --- stage B: 256 oc rows x 128B via gload_lds (coalesced, swizzled) ---
        #pragma unroll
        for (int r = 0; r < 8; ++r) {
            int pos = r * 256 + tid;
            int n = pos >> 3, uu = pos & 7;
            int s = uu ^ (n & 7);
            const char* src = wc + n * 4608 + c * 128 + s * 16;
            __builtin_amdgcn_global_load_lds(
                (const __attribute__((address_space(1))) unsigned int*)src,
                (__attribute__((address_space(3))) unsigned int*)(Bsb + pos * 16),
                16, 0, 0);
        }
        // --- stage A: gather + fp16 lerp + swizzled write ---
        int ks  = c >> 2;
        int cib = (c & 3) * 128;
        #pragma unroll
        for (int r = 0; r < 2; ++r) {
            int px = pxA0 + r * 32;
            unsigned b0 = row0[ks][px] + cib + sA * 16;
            unsigned b1 = row1[ks][px] + cib + sA * 16;
            float wy = wyv[ks][px];
            f16x8 v0 = *(const f16x8*)(featc + b0);
            f16x8 v1 = *(const f16x8*)(featc + b1);
            _Float16 wyh = (_Float16)wy;
            _Float16 omh = (_Float16)(1.0f - wy);
            f16x8 res = v0 * omh + v1 * wyh;
            *(f16x8*)(Asb + px * 128 + ((sA ^ (px & 7)) << 4)) = res;
        }
        __syncthreads();

        f16x8 av[4][2], bv[4][2];
        #pragma unroll
        for (int m = 0; m < 4; ++m) {
            av[m][0] = *(const f16x8*)(Asb + m * 2048 + rA + u0);
            av[m][1] = *(const f16x8*)(Asb + m * 2048 + rA + u1);
        }
        #pragma unroll
        for (int n = 0; n < 4; ++n) {
            bv[n][0] = *(const f16x8*)(Bsb + w * 8192 + n * 2048 + rA + u0);
            bv[n][1] = *(const f16x8*)(Bsb + w * 8192 + n * 2048 + rA + u1);
        }
        #pragma unroll
        for (int m = 0; m < 4; ++m)
            #pragma unroll
            for (int n = 0; n < 4; ++n) {
                acc[m][n] = __builtin_amdgcn_mfma_f32_16x16x32_f16(av[m][0], bv[n][0], acc[m][n], 0, 0, 0);
                acc[m][n] = __builtin_amdgcn_mfma_f32_16x16x32_f16(av[m][1], bv[n][1], acc[m][n], 0, 0, 0);
            }
        __syncthreads();
    }

    #pragma unroll
    for (int n = 0; n < 4; ++n) {
        int o = w * 64 + n * 16 + qc;
        float bvs = dsc_b[o];
        float* orow = out + ((size_t)(b * 256 + o) * 64 + wd) * 64;
        #pragma unroll
        for (int m = 0; m < 4; ++m) {
            int px = m * 16 + g * 4;
            float4 res;
            res.x = fmaxf(acc[m][n][0] + bvs, 0.0f);
            res.y = fmaxf(acc[m][n][1] + bvs, 0.0f);
            res.z = fmaxf(acc[m][n][2] + bvs, 0.0f);
            res.w = fmaxf(acc[m][n][3] + bvs, 0.0f);
            *(float4*)(orow + px) = res;
        }
    }
}

// ---------------------------------------------------------------------------
extern "C" void kernel_launch(void* const* d_in, const int* in_sizes, int n_in,
                              void* d_out, int out_size, void* d_ws, size_t ws_size,
                              hipStream_t stream) {
    (void)in_sizes; (void)n_in; (void)out_size; (void)ws_size;
    const float* x        = (const float*)d_in[0];
    const float* qkv_w    = (const float*)d_in[1];
    const float* qkv_b    = (const float*)d_in[2];
    const float* proj_w   = (const float*)d_in[3];
    const float* proj_b   = (const float*)d_in[4];
    const float* rel_bias = (const float*)d_in[5];
    const float* offset   = (const float*)d_in[6];
    const float* dsc_w    = (const float*)d_in[7];
    const float* dsc_b    = (const float*)d_in[8];
    float* out = (float*)d_out;

    unsigned short* wsu = (unsigned short*)d_ws;
    _Float16* qh = (_Float16*)wsu;                                  // 8.39M fp16
    _Float16* kh = (_Float16*)(wsu + NFLOAT_BUF);
    _Float16* vt = (_Float16*)(wsu + 2 * (size_t)NFLOAT_BUF);
    unsigned short* attn_ob = wsu + 3 * (size_t)NFLOAT_BUF;         // bf16
    _Float16* feath = (_Float16*)(wsu + 4 * (size_t)NFLOAT_BUF);    // fp16
    unsigned short* xb      = wsu + 5 * (size_t)NFLOAT_BUF;         // bf16
    unsigned short* wb      = wsu + 6 * (size_t)NFLOAT_BUF;         // 196608 bf16
    unsigned short* pwb     = wb + 196608;                          // 65536 bf16
    _Float16* wT2h          = (_Float16*)(pwb + 65536);             // 589824 fp16
    float* ymap = (float*)((unsigned short*)wT2h + 589824);         // 294912 f32

    cvt_bf16_kernel<<<4096, 256, 0, stream>>>(x, xb, 1048576);
    cvt_bf16_kernel<<<96, 256, 0, stream>>>(qkv_w, wb, 24576);
    cvt_bf16_kernel<<<32, 256, 0, stream>>>(proj_w, pwb, 8192);
    transpose_w_kernel<<<2304, 256, 0, stream>>>(dsc_w, wT2h);
    ymap_kernel<<<128, 256, 0, stream>>>(offset, ymap);
    qkv_mfma_kernel<<<dim3(3, 512), 256, 0, stream>>>(xb, wb, qkv_b, qh, kh, vt);
    attn_mfma_kernel<<<512, 512, 0, stream>>>(qh, kh, vt, rel_bias, attn_ob);
    proj_mfma_kernel<<<512, 256, 0, stream>>>(attn_ob, pwb, proj_b, feath);
    sample_conv_mfma3_kernel<<<512, 256, 0, stream>>>(feath, ymap, wT2h, dsc_b, out);
}

// Round 9
// 222.382 us; speedup vs baseline: 1.1312x; 1.0225x over previous
//
#include <hip/hip_runtime.h>
#include <math.h>

// Shapes: B=8, H=W=64, C=256, HEADS=8, d=32, WS=8, SS=4, K=9
// NTOK = 32768 tokens; 512 windows of 64 tokens.
// Conv = implicit GEMM: M=32768 px, N=256 oc, K=2304 (f16 MFMA, pipelined dbuf).
// QKV  = GEMM M=32768, N=768, K=256 (bf16 MFMA, fp16 outputs).
// Attn = per-window MFMA fp16: S^T = K·Q^T, O = P·V^T. 1 wave = 1 head.
// Proj = GEMM M=32768, N=256, K=256 (bf16 MFMA, fp16 feat output).

#define NFLOAT_BUF 8388608  // 32768*256

typedef float f32x4 __attribute__((ext_vector_type(4)));
typedef __bf16 bf16x8 __attribute__((ext_vector_type(8)));
typedef _Float16 f16x8 __attribute__((ext_vector_type(8)));

__device__ inline unsigned pack2_bf16(float a, float b) {
    union { float f; unsigned u; } ua, ub;
    ua.f = a; ub.f = b;
    unsigned ra = (ua.u + 0x7FFFu + ((ua.u >> 16) & 1u)) >> 16;
    unsigned rb = (ub.u + 0x7FFFu + ((ub.u >> 16) & 1u)) & 0xFFFF0000u;
    return (ra & 0xFFFFu) | rb;
}
__device__ inline unsigned short pack1_bf16(float a) {
    union { float f; unsigned u; } v;
    v.f = a;
    return (unsigned short)((v.u + 0x7FFFu + ((v.u >> 16) & 1u)) >> 16);
}

// ---------------------------------------------------------------------------
// fp32 -> bf16 bulk convert (8 elems/thread)
// ---------------------------------------------------------------------------
__global__ __launch_bounds__(256) void cvt_bf16_kernel(const float* __restrict__ src,
                                                       unsigned short* __restrict__ dst,
                                                       int n8) {
    int t = blockIdx.x * 256 + threadIdx.x;
    if (t >= n8) return;
    const float4* s = (const float4*)(src + (size_t)t * 8);
    float4 a = s[0], b = s[1];
    uint4 o;
    o.x = pack2_bf16(a.x, a.y); o.y = pack2_bf16(a.z, a.w);
    o.z = pack2_bf16(b.x, b.y); o.w = pack2_bf16(b.z, b.w);
    *(uint4*)(dst + (size_t)t * 8) = o;
}

// ---------------------------------------------------------------------------
// dsc_weight (O=256, I=256, K=9) -> wT2h fp16 [o][kk=k*256+i]
// ---------------------------------------------------------------------------
__global__ __launch_bounds__(256) void transpose_w_kernel(const float* __restrict__ w,
                                                          _Float16* __restrict__ wT) {
    int t = blockIdx.x * 256 + threadIdx.x;   // < 589824
    int o = t / 2304;
    int kk = t - o * 2304;
    int k = kk >> 8, i = kk & 255;
    wT[t] = (_Float16)w[(o * 256 + i) * 9 + k];
}

// ---------------------------------------------------------------------------
// snake coordinate map -> ymap[b][wd*9+k][hd]
// ---------------------------------------------------------------------------
__global__ __launch_bounds__(256) void ymap_kernel(const float* __restrict__ offset,
                                                   float* __restrict__ ymap) {
    int t = blockIdx.x * 256 + threadIdx.x;   // < 32768
    int hd = t & 63;
    int wd = (t >> 6) & 63;
    int b  = t >> 12;
    const float* op = offset + ((size_t)(b * 18) * 64 + wd) * 64 + hd;
    float yo[9];
    #pragma unroll
    for (int k = 0; k < 9; ++k) yo[k] = op[(size_t)k * 4096];
    float cum[9];
    cum[4] = 0.0f;
    float s = 0.0f;
    for (int j = 3; j >= 0; --j) { s += yo[j]; cum[j] = s; }
    s = 0.0f;
    for (int j = 5; j < 9; ++j) { s += yo[j]; cum[j] = s; }
    float wdf = (float)wd;
    float* yp = ymap + ((size_t)(b * 576 + wd * 9)) * 64 + hd;
    #pragma unroll
    for (int k = 0; k < 9; ++k) yp[(size_t)k * 64] = wdf + cum[k];
}

// ---------------------------------------------------------------------------
// QKV GEMM via bf16 MFMA. Block = 64 M-rows x 256 N. grid (3, 512).
// Outputs fp16: q,k as [win*8+h][l][32]; v transposed [win*8+h][32][64].
// ---------------------------------------------------------------------------
__global__ __launch_bounds__(256) void qkv_mfma_kernel(
    const unsigned short* __restrict__ xb, const unsigned short* __restrict__ wb,
    const float* __restrict__ qkv_b,
    _Float16* __restrict__ qh, _Float16* __restrict__ kh, _Float16* __restrict__ vt) {

    __shared__ __align__(16) char Asb[8192];    // 64 rows * 128B
    __shared__ __align__(16) char Bsb[32768];   // 256 rows * 128B
    __shared__ unsigned rowoff[64];

    int nb = blockIdx.x;          // 0..2  (q / k / v)
    int m0 = blockIdx.y * 64;
    int tid = threadIdx.x;
    int lane = tid & 63, w = tid >> 6;
    int gw = m0 >> 6;             // global window

    if (tid < 64) {
        int l = tid;
        int b = gw >> 6, win = gw & 63;
        int rh = ((win >> 3) << 3) + (l >> 3);
        int rw = ((win & 7) << 3) + (l & 7);
        int sh = (rh + 4) & 63, sw = (rw + 4) & 63;
        rowoff[l] = (unsigned)(((b * 64 + sh) * 64 + sw) * 512);  // byte offset
    }

    f32x4 acc[4][4];
    #pragma unroll
    for (int m = 0; m < 4; ++m)
        #pragma unroll
        for (int n = 0; n < 4; ++n) {
            f32x4 z = {0.0f, 0.0f, 0.0f, 0.0f};
            acc[m][n] = z;
        }

    const char* xc = (const char*)xb;
    const char* wc = (const char*)wb;
    int rA = (lane & 15) * 128;
    int u0 = (((lane >> 4)    ) ^ (lane & 7)) << 4;
    int u1 = ((4 + (lane >> 4)) ^ (lane & 7)) << 4;

    __syncthreads();

    for (int c = 0; c < 4; ++c) {   // K chunks of 64
        #pragma unroll
        for (int r = 0; r < 2; ++r) {
            int pos = r * 256 + tid;
            int row = pos >> 3, u = pos & 7;
            const char* src = xc + rowoff[row] + c * 128 + ((u ^ (row & 7)) << 4);
            __builtin_amdgcn_global_load_lds(
                (const __attribute__((address_space(1))) unsigned int*)src,
                (__attribute__((address_space(3))) unsigned int*)(Asb + pos * 16),
                16, 0, 0);
        }
        #pragma unroll
        for (int r = 0; r < 8; ++r) {
            int pos = r * 256 + tid;
            int n = pos >> 3, u = pos & 7;
            const char* src = wc + (size_t)(nb * 256 + n) * 512 + c * 128 + ((u ^ (n & 7)) << 4);
            __builtin_amdgcn_global_load_lds(
                (const __attribute__((address_space(1))) unsigned int*)src,
                (__attribute__((address_space(3))) unsigned int*)(Bsb + pos * 16),
                16, 0, 0);
        }
        __syncthreads();

        bf16x8 av[4][2], bv[4][2];
        #pragma unroll
        for (int m = 0; m < 4; ++m) {
            av[m][0] = *(const bf16x8*)(Asb + m * 2048 + rA + u0);
            av[m][1] = *(const bf16x8*)(Asb + m * 2048 + rA + u1);
        }
        #pragma unroll
        for (int n = 0; n < 4; ++n) {
            bv[n][0] = *(const bf16x8*)(Bsb + w * 8192 + n * 2048 + rA + u0);
            bv[n][1] = *(const bf16x8*)(Bsb + w * 8192 + n * 2048 + rA + u1);
        }
        #pragma unroll
        for (int m = 0; m < 4; ++m)
            #pragma unroll
            for (int n = 0; n < 4; ++n) {
                acc[m][n] = __builtin_amdgcn_mfma_f32_16x16x32_bf16(av[m][0], bv[n][0], acc[m][n], 0, 0, 0);
                acc[m][n] = __builtin_amdgcn_mfma_f32_16x16x32_bf16(av[m][1], bv[n][1], acc[m][n], 0, 0, 0);
            }
        __syncthreads();
    }

    float scale = (nb == 0) ? 0.17677669529663689f : 1.0f;
    #pragma unroll
    for (int nf = 0; nf < 4; ++nf) {
        int o = w * 64 + nf * 16 + (lane & 15);
        float bias = qkv_b[nb * 256 + o];
        int hh = o >> 5, dd = o & 31;
        if (nb < 2) {
            _Float16* dstb = (nb == 0) ? qh : kh;
            _Float16* base = dstb + ((size_t)(gw * 8 + hh) * 64) * 32 + dd;
            #pragma unroll
            for (int mf = 0; mf < 4; ++mf) {
                int l0 = mf * 16 + (lane >> 4) * 4;
                #pragma unroll
                for (int j = 0; j < 4; ++j)
                    base[(size_t)(l0 + j) * 32] = (_Float16)((acc[mf][nf][j] + bias) * scale);
            }
        } else {
            _Float16* base = vt + ((size_t)(gw * 8 + hh) * 32 + dd) * 64;
            #pragma unroll
            for (int mf = 0; mf < 4; ++mf) {
                int l0 = mf * 16 + (lane >> 4) * 4;
                union { _Float16 x[4]; uint2 u; } pk;
                #pragma unroll
                for (int j = 0; j < 4; ++j) pk.x[j] = (_Float16)(acc[mf][nf][j] + bias);
                *(uint2*)(base + l0) = pk.u;
            }
        }
    }
}

// ---------------------------------------------------------------------------
// Attention via fp16 MFMA. Block = 1 window, 512 threads = 8 waves = 8 heads.
// ---------------------------------------------------------------------------
__global__ __launch_bounds__(512) void attn_mfma_kernel(
    const _Float16* __restrict__ qh, const _Float16* __restrict__ kh,
    const _Float16* __restrict__ vt, const float* __restrict__ rel_bias,
    unsigned short* __restrict__ attn_ob) {

    __shared__ __align__(16) char Plds[65536];   // 8 waves x 64 rows x 128B
    int n = blockIdx.x;
    int win = n & 63;
    int wy = win >> 3, wx = win & 7;
    int tid = threadIdx.x, lane = tid & 63, h = tid >> 6;
    int qc = lane & 15, g = lane >> 4;
    char* P = Plds + h * 8192;

    const _Float16* qp = qh + (size_t)(n * 8 + h) * 2048;
    const _Float16* kp = kh + (size_t)(n * 8 + h) * 2048;
    const _Float16* vp = vt + (size_t)(n * 8 + h) * 2048;
    const float* rb = rel_bias + (size_t)h * 4096;

    int rk[16];
    #pragma unroll
    for (int mt = 0; mt < 4; ++mt)
        #pragma unroll
        for (int j = 0; j < 4; ++j) {
            int key = mt * 16 + g * 4 + j;
            int rh = wy * 8 + (key >> 3), rw = wx * 8 + (key & 7);
            rk[mt * 4 + j] = (rh < 56 ? 0 : (rh < 60 ? 1 : 2)) * 3
                           + (rw < 56 ? 0 : (rw < 60 ? 1 : 2));
        }

    f16x8 kf[4];
    #pragma unroll
    for (int mt = 0; mt < 4; ++mt)
        kf[mt] = *(const f16x8*)(kp + (mt * 16 + qc) * 32 + g * 8);

    #pragma unroll
    for (int nt = 0; nt < 4; ++nt) {
        int q = nt * 16 + qc;
        int rqh = wy * 8 + (q >> 3), rqw = wx * 8 + (q & 7);
        int rq = (rqh < 56 ? 0 : (rqh < 60 ? 1 : 2)) * 3
               + (rqw < 56 ? 0 : (rqw < 60 ? 1 : 2));
        f16x8 qf = *(const f16x8*)(qp + q * 32 + g * 8);

        f32x4 s[4];
        #pragma unroll
        for (int mt = 0; mt < 4; ++mt) {
            f32x4 z = {0.0f, 0.0f, 0.0f, 0.0f};
            s[mt] = __builtin_amdgcn_mfma_f32_16x16x32_f16(kf[mt], qf, z, 0, 0, 0);
        }

        float vals[16];
        #pragma unroll
        for (int mt = 0; mt < 4; ++mt) {
            float4 bv4 = *(const float4*)(rb + q * 64 + mt * 16 + g * 4);
            vals[mt * 4 + 0] = s[mt][0] + bv4.x + (rk[mt * 4 + 0] != rq ? -100.0f : 0.0f);
            vals[mt * 4 + 1] = s[mt][1] + bv4.y + (rk[mt * 4 + 1] != rq ? -100.0f : 0.0f);
            vals[mt * 4 + 2] = s[mt][2] + bv4.z + (rk[mt * 4 + 2] != rq ? -100.0f : 0.0f);
            vals[mt * 4 + 3] = s[mt][3] + bv4.w + (rk[mt * 4 + 3] != rq ? -100.0f : 0.0f);
        }

        float mx = vals[0];
        #pragma unroll
        for (int i = 1; i < 16; ++i) mx = fmaxf(mx, vals[i]);
        mx = fmaxf(mx, __shfl_xor(mx, 16));
        mx = fmaxf(mx, __shfl_xor(mx, 32));

        float sum = 0.0f;
        #pragma unroll
        for (int i = 0; i < 16; ++i) { vals[i] = __expf(vals[i] - mx); sum += vals[i]; }
        sum += __shfl_xor(sum, 16);
        sum += __shfl_xor(sum, 32);
        float inv = 1.0f / sum;

        #pragma unroll
        for (int mt = 0; mt < 4; ++mt) {
            union { _Float16 x[4]; uint2 u; } pk4;
            #pragma unroll
            for (int j = 0; j < 4; ++j) pk4.x[j] = (_Float16)(vals[mt * 4 + j] * inv);
            int off = (mt * 32 + g * 8) ^ ((q & 7) << 4);
            *(uint2*)(P + q * 128 + off) = pk4.u;
        }
    }

    f16x8 pa[4][2];
    #pragma unroll
    for (int im = 0; im < 4; ++im)
        #pragma unroll
        for (int ks = 0; ks < 2; ++ks) {
            int row = im * 16 + qc;
            int off = (ks * 64 + g * 16) ^ ((row & 7) << 4);
            pa[im][ks] = *(const f16x8*)(P + row * 128 + off);
        }
    f16x8 bvv[2][2];
    #pragma unroll
    for (int in = 0; in < 2; ++in)
        #pragma unroll
        for (int ks = 0; ks < 2; ++ks)
            bvv[in][ks] = *(const f16x8*)(vp + (in * 16 + qc) * 64 + ks * 32 + g * 8);

    f32x4 acc[4][2];
    #pragma unroll
    for (int im = 0; im < 4; ++im)
        #pragma unroll
        for (int in = 0; in < 2; ++in) {
            f32x4 z = {0.0f, 0.0f, 0.0f, 0.0f};
            acc[im][in] = z;
        }
    #pragma unroll
    for (int im = 0; im < 4; ++im)
        #pragma unroll
        for (int in = 0; in < 2; ++in) {
            acc[im][in] = __builtin_amdgcn_mfma_f32_16x16x32_f16(pa[im][0], bvv[in][0], acc[im][in], 0, 0, 0);
            acc[im][in] = __builtin_amdgcn_mfma_f32_16x16x32_f16(pa[im][1], bvv[in][1], acc[im][in], 0, 0, 0);
        }

    #pragma unroll
    for (int im = 0; im < 4; ++im)
        #pragma unroll
        for (int in = 0; in < 2; ++in)
            #pragma unroll
            for (int j = 0; j < 4; ++j) {
                int q2 = im * 16 + g * 4 + j;
                attn_ob[(size_t)(n * 64 + q2) * 256 + h * 32 + in * 16 + qc] =
                    pack1_bf16(acc[im][in][j]);
            }
}

// ---------------------------------------------------------------------------
// Proj GEMM via bf16 MFMA. Block = 64 M x 256 N. grid 512. fp16 feat output.
// ---------------------------------------------------------------------------
__global__ __launch_bounds__(256) void proj_mfma_kernel(
    const unsigned short* __restrict__ attn_ob, const unsigned short* __restrict__ pwb,
    const float* __restrict__ proj_b, _Float16* __restrict__ feath) {

    __shared__ __align__(16) char Asb[8192];
    __shared__ __align__(16) char Bsb[32768];

    int m0 = blockIdx.x * 64;
    int tid = threadIdx.x;
    int lane = tid & 63, w = tid >> 6;
    int gw = m0 >> 6;
    int bidx = gw >> 6, win = gw & 63;

    f32x4 acc[4][4];
    #pragma unroll
    for (int m = 0; m < 4; ++m)
        #pragma unroll
        for (int n = 0; n < 4; ++n) {
            f32x4 z = {0.0f, 0.0f, 0.0f, 0.0f};
            acc[m][n] = z;
        }

    const char* ac = (const char*)attn_ob;
    const char* wc = (const char*)pwb;
    int rA = (lane & 15) * 128;
    int u0 = (((lane >> 4)    ) ^ (lane & 7)) << 4;
    int u1 = ((4 + (lane >> 4)) ^ (lane & 7)) << 4;

    for (int c = 0; c < 4; ++c) {
        #pragma unroll
        for (int r = 0; r < 2; ++r) {
            int pos = r * 256 + tid;
            int row = pos >> 3, u = pos & 7;
            const char* src = ac + (size_t)(m0 + row) * 512 + c * 128 + ((u ^ (row & 7)) << 4);
            __builtin_amdgcn_global_load_lds(
                (const __attribute__((address_space(1))) unsigned int*)src,
                (__attribute__((address_space(3))) unsigned int*)(Asb + pos * 16),
                16, 0, 0);
        }
        #pragma unroll
        for (int r = 0; r < 8; ++r) {
            int pos = r * 256 + tid;
            int n = pos >> 3, u = pos & 7;
            const char* src = wc + (size_t)n * 512 + c * 128 + ((u ^ (n & 7)) << 4);
            __builtin_amdgcn_global_load_lds(
                (const __attribute__((address_space(1))) unsigned int*)src,
                (__attribute__((address_space(3))) unsigned int*)(Bsb + pos * 16),
                16, 0, 0);
        }
        __syncthreads();

        bf16x8 av[4][2], bv[4][2];
        #pragma unroll
        for (int m = 0; m < 4; ++m) {
            av[m][0] = *(const bf16x8*)(Asb + m * 2048 + rA + u0);
            av[m][1] = *(const bf16x8*)(Asb + m * 2048 + rA + u1);
        }
        #pragma unroll
        for (int n = 0; n < 4; ++n) {
            bv[n][0] = *(const bf16x8*)(Bsb + w * 8192 + n * 2048 + rA + u0);
            bv[n][1] = *(const bf16x8*)(Bsb + w * 8192 + n * 2048 + rA + u1);
        }
        #pragma unroll
        for (int m = 0; m < 4; ++m)
            #pragma unroll
            for (int n = 0; n < 4; ++n) {
                acc[m][n] = __builtin_amdgcn_mfma_f32_16x16x32_bf16(av[m][0], bv[n][0], acc[m][n], 0, 0, 0);
                acc[m][n] = __builtin_amdgcn_mfma_f32_16x16x32_bf16(av[m][1], bv[n][1], acc[m][n], 0, 0, 0);
            }
        __syncthreads();
    }

    #pragma unroll
    for (int nf = 0; nf < 4; ++nf) {
        int f = w * 64 + nf * 16 + (lane & 15);
        float bias = proj_b[f];
        #pragma unroll
        for (int mf = 0; mf < 4; ++mf) {
            #pragma unroll
            for (int j = 0; j < 4; ++j) {
                int px = mf * 16 + (lane >> 4) * 4 + j;
                int rh = ((win >> 3) << 3) + (px >> 3);
                int rw = ((win & 7) << 3) + (px & 7);
                int p = (rh + 4) & 63;
                int qq = (rw + 4) & 63;
                feath[((size_t)(bidx * 64 + p) * 64 + qq) * 256 + f] =
                    (_Float16)(acc[mf][nf][j] + bias);
            }
        }
    }
}

// ---------------------------------------------------------------------------
// Fused bilinear-sample + conv, f16 MFMA implicit GEMM, v4 (pipelined):
//  Block = 128 px (2 wd rows) x 256 oc, 512 threads = 8 waves (2 px-half x 4 oc-q).
//  grid 256 = 1 block/CU. Double-buffered A(16KB) and B(32KB) LDS.
//  Steady state per iter (ONE barrier): issue B(c+1) gload_lds + A(c+1)
//  global->reg loads FIRST; ds_read+MFMA on buf[cur] hides the latency;
//  lerp+ds_write A[nxt]; __syncthreads (drain is cheap by then).
// ---------------------------------------------------------------------------
__global__ __launch_bounds__(512) void sample_conv_mfma4_kernel(
    const _Float16* __restrict__ feath, const float* __restrict__ ymap,
    const _Float16* __restrict__ wT2h, const float* __restrict__ dsc_b,
    float* __restrict__ out) {

    __shared__ __align__(16) char Ab[2][16384];   // 128 px * 128B
    __shared__ __align__(16) char Bb[2][32768];   // 256 oc * 128B
    __shared__ unsigned row0[2][9][64];
    __shared__ unsigned row1[2][9][64];
    __shared__ float    wyv[2][9][64];

    int blk = blockIdx.x;              // 0..255; XCD swizzle
    int b = blk & 7, wd0 = (blk >> 3) * 2;
    int tid = threadIdx.x;
    int lane = tid & 63, w = tid >> 6;
    int qc = lane & 15, g = lane >> 4;
    int ph = w >> 2, nq = w & 3;       // px half, oc quarter

    for (int idx = tid; idx < 1152; idx += 512) {
        int wdl = idx / 576;
        int r = idx - wdl * 576;
        int k = r >> 6, hd = r & 63;
        int wd = wd0 + wdl;
        float y = ymap[((size_t)(b * 576 + wd * 9 + k)) * 64 + hd];
        y = fminf(fmaxf(y, 0.0f), 63.0f);
        float y0f = floorf(y);
        int y0 = (int)y0f;
        int y1 = min(y0 + 1, 63);
        int xc = min(max(hd + k - 4, 0), 63);
        row0[wdl][k][hd] = (unsigned)(((b * 64 + y0) * 64 + xc) * 512);  // byte off
        row1[wdl][k][hd] = (unsigned)(((b * 64 + y1) * 64 + xc) * 512);
        wyv[wdl][k][hd] = y - y0f;
    }

    f32x4 acc[4][4];
    #pragma unroll
    for (int m = 0; m < 4; ++m)
        #pragma unroll
        for (int n = 0; n < 4; ++n) {
            f32x4 z = {0.0f, 0.0f, 0.0f, 0.0f};
            acc[m][n] = z;
        }

    const char* featc = (const char*)feath;
    const char* wc    = (const char*)wT2h;

    // A-stage decode: 2 slots/thread. pos = r*512+tid -> px = pos>>3, sA = pos&7
    int pxA[2], sAv[2];
    #pragma unroll
    for (int r = 0; r < 2; ++r) {
        int pos = r * 512 + tid;
        pxA[r] = pos >> 3;
        sAv[r] = pos & 7;
    }

    int rAa = qc * 128;                 // A frag: row within px-half
    int u0 = ((g    ) ^ (qc & 7)) << 4;
    int u1 = ((4 + g) ^ (qc & 7)) << 4;

    __syncthreads();   // tables ready

    // ---- prologue: stage A(0), B(0) into buf 0 ----
    #pragma unroll
    for (int r = 0; r < 4; ++r) {       // B: 4 slots/thread
        int pos = r * 512 + tid;
        int n = pos >> 3, uu = pos & 7;
        const char* src = wc + n * 4608 + 0 * 128 + ((uu ^ (n & 7)) << 4);
        __builtin_amdgcn_global_load_lds(
            (const __attribute__((address_space(1))) unsigned int*)src,
            (__attribute__((address_space(3))) unsigned int*)(Bb[0] + pos * 16),
            16, 0, 0);
    }
    #pragma unroll
    for (int r = 0; r < 2; ++r) {
        int px = pxA[r], sA = sAv[r];
        int wdl = px >> 6, hd = px & 63;
        unsigned b0 = row0[wdl][0][hd] + sA * 16;
        unsigned b1 = row1[wdl][0][hd] + sA * 16;
        float wy = wyv[wdl][0][hd];
        f16x8 v0 = *(const f16x8*)(featc + b0);
        f16x8 v1 = *(const f16x8*)(featc + b1);
        _Float16 wyh = (_Float16)wy;
        _Float16 omh = (_Float16)(1.0f - wy);
        f16x8 res = v0 * omh + v1 * wyh;
        *(f16x8*)(Ab[0] + px * 128 + ((sA ^ (px & 7)) << 4)) = res;
    }
    __syncthreads();

    for (int c = 0; c < 36; ++c) {
        int cur = c & 1, nxt = cur ^ 1;

        // ---- issue next-tile stages FIRST (latency hidden by MFMA below) ----
        f16x8 s0[2], s1[2];
        float swy[2];
        if (c < 35) {
            int cn = c + 1;
            int ks = cn >> 2, cib = (cn & 3) * 128;
            #pragma unroll
            for (int r = 0; r < 4; ++r) {
                int pos = r * 512 + tid;
                int n = pos >> 3, uu = pos & 7;
                const char* src = wc + n * 4608 + cn * 128 + ((uu ^ (n & 7)) << 4);
                __builtin_amdgcn_global_load_lds(
                    (const __attribute__((address_space(1))) unsigned int*)src,
                    (__attribute__((address_space(3))) unsigned int*)(Bb[nxt] + pos * 16),
                    16, 0, 0);
            }
            #pragma unroll
            for (int r = 0; r < 2; ++r) {
                int px = pxA[r], sA = sAv[r];
                int wdl = px >> 6, hd = px & 63;
                unsigned b0 = row0[wdl][ks][hd] + cib + sA * 16;
                unsigned b1 = row1[wdl][ks][hd] + cib + sA * 16;
                swy[r] = wyv[wdl][ks][hd];
                s0[r] = *(const f16x8*)(featc + b0);
                s1[r] = *(const f16x8*)(featc + b1);
            }
        }

        // ---- compute on current buffers ----
        f16x8 av[4][2], bv[4][2];
        #pragma unroll
        for (int m = 0; m < 4; ++m) {
            char* abase = Ab[cur] + ph * 8192 + m * 2048 + rAa;
            av[m][0] = *(const f16x8*)(abase + u0);
            av[m][1] = *(const f16x8*)(abase + u1);
        }
        #pragma unroll
        for (int n = 0; n < 4; ++n) {
            char* bbase = Bb[cur] + nq * 8192 + n * 2048 + rAa;
            bv[n][0] = *(const f16x8*)(bbase + u0);
            bv[n][1] = *(const f16x8*)(bbase + u1);
        }
        #pragma unroll
        for (int m = 0; m < 4; ++m)
            #pragma unroll
            for (int n = 0; n < 4; ++n) {
                acc[m][n] = __builtin_amdgcn_mfma_f32_16x16x32_f16(av[m][0], bv[n][0], acc[m][n], 0, 0, 0);
                acc[m][n] = __builtin_amdgcn_mfma_f32_16x16x32_f16(av[m][1], bv[n][1], acc[m][n], 0, 0, 0);
            }

        // ---- finish A(c+1): lerp + swizzled ds_write ----
        if (c < 35) {
            #pragma unroll
            for (int r = 0; r < 2; ++r) {
                int px = pxA[r], sA = sAv[r];
                _Float16 wyh = (_Float16)swy[r];
                _Float16 omh = (_Float16)(1.0f - swy[r]);
                f16x8 res = s0[r] * omh + s1[r] * wyh;
                *(f16x8*)(Ab[nxt] + px * 128 + ((sA ^ (px & 7)) << 4)) = res;
            }
        }
        __syncthreads();   // one barrier/iter: drains vmcnt (cheap now) + lds
    }

    #pragma unroll
    for (int n = 0; n < 4; ++n) {
        int o = nq * 64 + n * 16 + qc;
        float bvs = dsc_b[o];
        float* orow = out + ((size_t)(b * 256 + o) * 64 + (wd0 + ph)) * 64;
        #pragma unroll
        for (int m = 0; m < 4; ++m) {
            int px = m * 16 + g * 4;
            float4 res;
            res.x = fmaxf(acc[m][n][0] + bvs, 0.0f);
            res.y = fmaxf(acc[m][n][1] + bvs, 0.0f);
            res.z = fmaxf(acc[m][n][2] + bvs, 0.0f);
            res.w = fmaxf(acc[m][n][3] + bvs, 0.0f);
            *(float4*)(orow + px) = res;
        }
    }
}

// ---------------------------------------------------------------------------
extern "C" void kernel_launch(void* const* d_in, const int* in_sizes, int n_in,
                              void* d_out, int out_size, void* d_ws, size_t ws_size,
                              hipStream_t stream) {
    (void)in_sizes; (void)n_in; (void)out_size; (void)ws_size;
    const float* x        = (const float*)d_in[0];
    const float* qkv_w    = (const float*)d_in[1];
    const float* qkv_b    = (const float*)d_in[2];
    const float* proj_w   = (const float*)d_in[3];
    const float* proj_b   = (const float*)d_in[4];
    const float* rel_bias = (const float*)d_in[5];
    const float* offset   = (const float*)d_in[6];
    const float* dsc_w    = (const float*)d_in[7];
    const float* dsc_b    = (const float*)d_in[8];
    float* out = (float*)d_out;

    unsigned short* wsu = (unsigned short*)d_ws;
    _Float16* qh = (_Float16*)wsu;                                  // 8.39M fp16
    _Float16* kh = (_Float16*)(wsu + NFLOAT_BUF);
    _Float16* vt = (_Float16*)(wsu + 2 * (size_t)NFLOAT_BUF);
    unsigned short* attn_ob = wsu + 3 * (size_t)NFLOAT_BUF;         // bf16
    _Float16* feath = (_Float16*)(wsu + 4 * (size_t)NFLOAT_BUF);    // fp16
    unsigned short* xb      = wsu + 5 * (size_t)NFLOAT_BUF;         // bf16
    unsigned short* wb      = wsu + 6 * (size_t)NFLOAT_BUF;         // 196608 bf16
    unsigned short* pwb     = wb + 196608;                          // 65536 bf16
    _Float16* wT2h          = (_Float16*)(pwb + 65536);             // 589824 fp16
    float* ymap = (float*)((unsigned short*)wT2h + 589824);         // 294912 f32

    cvt_bf16_kernel<<<4096, 256, 0, stream>>>(x, xb, 1048576);
    cvt_bf16_kernel<<<96, 256, 0, stream>>>(qkv_w, wb, 24576);
    cvt_bf16_kernel<<<32, 256, 0, stream>>>(proj_w, pwb, 8192);
    transpose_w_kernel<<<2304, 256, 0, stream>>>(dsc_w, wT2h);
    ymap_kernel<<<128, 256, 0, stream>>>(offset, ymap);
    qkv_mfma_kernel<<<dim3(3, 512), 256, 0, stream>>>(xb, wb, qkv_b, qh, kh, vt);
    attn_mfma_kernel<<<512, 512, 0, stream>>>(qh, kh, vt, rel_bias, attn_ob);
    proj_mfma_kernel<<<512, 256, 0, stream>>>(attn_ob, pwb, proj_b, feath);
    sample_conv_mfma4_kernel<<<256, 512, 0, stream>>>(feath, ymap, wT2h, dsc_b, out);
}

// Round 10
// 204.661 us; speedup vs baseline: 1.2292x; 1.0866x over previous
//
#include <hip/hip_runtime.h>
#include <math.h>

// Shapes: B=8, H=W=64, C=256, HEADS=8, d=32, WS=8, SS=4, K=9
// Pipeline: prep (cvt/transpose/ymap, 1 kernel) -> qkv (bf16 MFMA) ->
//           attn+proj fused (f16 MFMA, window-resident in LDS) ->
//           sample+conv (f16 MFMA, pipelined dbuf).

#define NFLOAT_BUF 8388608  // 32768*256

typedef float f32x4 __attribute__((ext_vector_type(4)));
typedef __bf16 bf16x8 __attribute__((ext_vector_type(8)));
typedef _Float16 f16x8 __attribute__((ext_vector_type(8)));

__device__ inline unsigned pack2_bf16(float a, float b) {
    union { float f; unsigned u; } ua, ub;
    ua.f = a; ub.f = b;
    unsigned ra = (ua.u + 0x7FFFu + ((ua.u >> 16) & 1u)) >> 16;
    unsigned rb = (ub.u + 0x7FFFu + ((ub.u >> 16) & 1u)) & 0xFFFF0000u;
    return (ra & 0xFFFFu) | rb;
}

// ---------------------------------------------------------------------------
// prep: all input conversions in ONE launch, partitioned by blockIdx.
//  [0,4096)    : x fp32 -> xb bf16            (1048576 x 8 elems)
//  [4096,4192) : qkv_w fp32 -> wb bf16        (24576 x 8)
//  [4192,4224) : proj_w fp32 -> pwh fp16      (8192 x 8)
//  [4224,6528) : dsc_w transpose -> wT2h fp16 [o][k*256+i]
//  [6528,6656) : snake ymap
// ---------------------------------------------------------------------------
__global__ __launch_bounds__(256) void prep_kernel(
    const float* __restrict__ x, unsigned short* __restrict__ xb,
    const float* __restrict__ qkv_w, unsigned short* __restrict__ wb,
    const float* __restrict__ proj_w, _Float16* __restrict__ pwh,
    const float* __restrict__ dsc_w, _Float16* __restrict__ wT,
    const float* __restrict__ offset, float* __restrict__ ymap) {
    int bid = blockIdx.x, tid = threadIdx.x;
    if (bid < 4096) {
        int t = bid * 256 + tid;
        const float4* s = (const float4*)(x + (size_t)t * 8);
        float4 a = s[0], b = s[1];
        uint4 o;
        o.x = pack2_bf16(a.x, a.y); o.y = pack2_bf16(a.z, a.w);
        o.z = pack2_bf16(b.x, b.y); o.w = pack2_bf16(b.z, b.w);
        *(uint4*)(xb + (size_t)t * 8) = o;
    } else if (bid < 4192) {
        int t = (bid - 4096) * 256 + tid;
        if (t < 24576) {
            const float4* s = (const float4*)(qkv_w + (size_t)t * 8);
            float4 a = s[0], b = s[1];
            uint4 o;
            o.x = pack2_bf16(a.x, a.y); o.y = pack2_bf16(a.z, a.w);
            o.z = pack2_bf16(b.x, b.y); o.w = pack2_bf16(b.z, b.w);
            *(uint4*)(wb + (size_t)t * 8) = o;
        }
    } else if (bid < 4224) {
        int t = (bid - 4192) * 256 + tid;
        if (t < 8192) {
            const float4* s = (const float4*)(proj_w + (size_t)t * 8);
            float4 a = s[0], b = s[1];
            union { _Float16 h[8]; uint4 u; } o;
            o.h[0] = (_Float16)a.x; o.h[1] = (_Float16)a.y;
            o.h[2] = (_Float16)a.z; o.h[3] = (_Float16)a.w;
            o.h[4] = (_Float16)b.x; o.h[5] = (_Float16)b.y;
            o.h[6] = (_Float16)b.z; o.h[7] = (_Float16)b.w;
            *(uint4*)(pwh + (size_t)t * 8) = o.u;
        }
    } else if (bid < 6528) {
        int t = (bid - 4224) * 256 + tid;   // < 589824
        int o = t / 2304;
        int kk = t - o * 2304;
        int k = kk >> 8, i = kk & 255;
        wT[t] = (_Float16)dsc_w[(o * 256 + i) * 9 + k];
    } else {
        int t = (bid - 6528) * 256 + tid;   // < 32768
        int hd = t & 63;
        int wd = (t >> 6) & 63;
        int b  = t >> 12;
        const float* op = offset + ((size_t)(b * 18) * 64 + wd) * 64 + hd;
        float yo[9];
        #pragma unroll
        for (int k = 0; k < 9; ++k) yo[k] = op[(size_t)k * 4096];
        float cum[9];
        cum[4] = 0.0f;
        float s = 0.0f;
        for (int j = 3; j >= 0; --j) { s += yo[j]; cum[j] = s; }
        s = 0.0f;
        for (int j = 5; j < 9; ++j) { s += yo[j]; cum[j] = s; }
        float wdf = (float)wd;
        float* yp = ymap + ((size_t)(b * 576 + wd * 9)) * 64 + hd;
        #pragma unroll
        for (int k = 0; k < 9; ++k) yp[(size_t)k * 64] = wdf + cum[k];
    }
}

// ---------------------------------------------------------------------------
// QKV GEMM via bf16 MFMA. Block = 64 M-rows x 256 N. grid (3, 512).
// Outputs fp16: q,k as [win*8+h][l][32]; v transposed [win*8+h][32][64].
// ---------------------------------------------------------------------------
__global__ __launch_bounds__(256) void qkv_mfma_kernel(
    const unsigned short* __restrict__ xb, const unsigned short* __restrict__ wb,
    const float* __restrict__ qkv_b,
    _Float16* __restrict__ qh, _Float16* __restrict__ kh, _Float16* __restrict__ vt) {

    __shared__ __align__(16) char Asb[8192];    // 64 rows * 128B
    __shared__ __align__(16) char Bsb[32768];   // 256 rows * 128B
    __shared__ unsigned rowoff[64];

    int nb = blockIdx.x;          // 0..2  (q / k / v)
    int m0 = blockIdx.y * 64;
    int tid = threadIdx.x;
    int lane = tid & 63, w = tid >> 6;
    int gw = m0 >> 6;             // global window

    if (tid < 64) {
        int l = tid;
        int b = gw >> 6, win = gw & 63;
        int rh = ((win >> 3) << 3) + (l >> 3);
        int rw = ((win & 7) << 3) + (l & 7);
        int sh = (rh + 4) & 63, sw = (rw + 4) & 63;
        rowoff[l] = (unsigned)(((b * 64 + sh) * 64 + sw) * 512);  // byte offset
    }

    f32x4 acc[4][4];
    #pragma unroll
    for (int m = 0; m < 4; ++m)
        #pragma unroll
        for (int n = 0; n < 4; ++n) {
            f32x4 z = {0.0f, 0.0f, 0.0f, 0.0f};
            acc[m][n] = z;
        }

    const char* xc = (const char*)xb;
    const char* wc = (const char*)wb;
    int rA = (lane & 15) * 128;
    int u0 = (((lane >> 4)    ) ^ (lane & 7)) << 4;
    int u1 = ((4 + (lane >> 4)) ^ (lane & 7)) << 4;

    __syncthreads();

    for (int c = 0; c < 4; ++c) {   // K chunks of 64
        #pragma unroll
        for (int r = 0; r < 2; ++r) {
            int pos = r * 256 + tid;
            int row = pos >> 3, u = pos & 7;
            const char* src = xc + rowoff[row] + c * 128 + ((u ^ (row & 7)) << 4);
            __builtin_amdgcn_global_load_lds(
                (const __attribute__((address_space(1))) unsigned int*)src,
                (__attribute__((address_space(3))) unsigned int*)(Asb + pos * 16),
                16, 0, 0);
        }
        #pragma unroll
        for (int r = 0; r < 8; ++r) {
            int pos = r * 256 + tid;
            int n = pos >> 3, u = pos & 7;
            const char* src = wc + (size_t)(nb * 256 + n) * 512 + c * 128 + ((u ^ (n & 7)) << 4);
            __builtin_amdgcn_global_load_lds(
                (const __attribute__((address_space(1))) unsigned int*)src,
                (__attribute__((address_space(3))) unsigned int*)(Bsb + pos * 16),
                16, 0, 0);
        }
        __syncthreads();

        bf16x8 av[4][2], bv[4][2];
        #pragma unroll
        for (int m = 0; m < 4; ++m) {
            av[m][0] = *(const bf16x8*)(Asb + m * 2048 + rA + u0);
            av[m][1] = *(const bf16x8*)(Asb + m * 2048 + rA + u1);
        }
        #pragma unroll
        for (int n = 0; n < 4; ++n) {
            bv[n][0] = *(const bf16x8*)(Bsb + w * 8192 + n * 2048 + rA + u0);
            bv[n][1] = *(const bf16x8*)(Bsb + w * 8192 + n * 2048 + rA + u1);
        }
        #pragma unroll
        for (int m = 0; m < 4; ++m)
            #pragma unroll
            for (int n = 0; n < 4; ++n) {
                acc[m][n] = __builtin_amdgcn_mfma_f32_16x16x32_bf16(av[m][0], bv[n][0], acc[m][n], 0, 0, 0);
                acc[m][n] = __builtin_amdgcn_mfma_f32_16x16x32_bf16(av[m][1], bv[n][1], acc[m][n], 0, 0, 0);
            }
        __syncthreads();
    }

    float scale = (nb == 0) ? 0.17677669529663689f : 1.0f;
    #pragma unroll
    for (int nf = 0; nf < 4; ++nf) {
        int o = w * 64 + nf * 16 + (lane & 15);
        float bias = qkv_b[nb * 256 + o];
        int hh = o >> 5, dd = o & 31;
        if (nb < 2) {
            _Float16* dstb = (nb == 0) ? qh : kh;
            _Float16* base = dstb + ((size_t)(gw * 8 + hh) * 64) * 32 + dd;
            #pragma unroll
            for (int mf = 0; mf < 4; ++mf) {
                int l0 = mf * 16 + (lane >> 4) * 4;
                #pragma unroll
                for (int j = 0; j < 4; ++j)
                    base[(size_t)(l0 + j) * 32] = (_Float16)((acc[mf][nf][j] + bias) * scale);
            }
        } else {
            _Float16* base = vt + ((size_t)(gw * 8 + hh) * 32 + dd) * 64;
            #pragma unroll
            for (int mf = 0; mf < 4; ++mf) {
                int l0 = mf * 16 + (lane >> 4) * 4;
                union { _Float16 x[4]; uint2 u; } pk;
                #pragma unroll
                for (int j = 0; j < 4; ++j) pk.x[j] = (_Float16)(acc[mf][nf][j] + bias);
                *(uint2*)(base + l0) = pk.u;
            }
        }
    }
}

// ---------------------------------------------------------------------------
// Fused attention + proj. Block = 1 window, 512 threads = 8 waves.
// Phase 1 (attn, per-wave head, no barriers): S^T=mfma(K,Q), softmax in-reg,
//   P via swizzled LDS, O=mfma(P,V^T). Epilogue -> aob LDS (proj-A swizzle).
// Phase 2 (proj): A=aob (LDS-resident), B=pwh staged via gload_lds,
//   f16 MFMA, un-window+un-roll epilogue -> feath fp16.
// LDS reuse: P (64KB, dead after PV) overlaid by aob(32K)+Bsb(32K).
// ---------------------------------------------------------------------------
__global__ __launch_bounds__(512, 4) void attn_proj_kernel(
    const _Float16* __restrict__ qh, const _Float16* __restrict__ kh,
    const _Float16* __restrict__ vt, const float* __restrict__ rel_bias,
    const _Float16* __restrict__ pwh, const float* __restrict__ proj_b,
    _Float16* __restrict__ feath) {

    __shared__ __align__(16) char SH[65536];
    int n = blockIdx.x;
    int win = n & 63;
    int wy = win >> 3, wx = win & 7;
    int tid = threadIdx.x, lane = tid & 63, h = tid >> 6;
    int qc = lane & 15, g = lane >> 4;
    char* P = SH + h * 8192;

    const _Float16* qp = qh + (size_t)(n * 8 + h) * 2048;
    const _Float16* kp = kh + (size_t)(n * 8 + h) * 2048;
    const _Float16* vp = vt + (size_t)(n * 8 + h) * 2048;
    const float* rb = rel_bias + (size_t)h * 4096;

    // ---------- phase 1: attention ----------
    int rk[16];
    #pragma unroll
    for (int mt = 0; mt < 4; ++mt)
        #pragma unroll
        for (int j = 0; j < 4; ++j) {
            int key = mt * 16 + g * 4 + j;
            int rh = wy * 8 + (key >> 3), rw = wx * 8 + (key & 7);
            rk[mt * 4 + j] = (rh < 56 ? 0 : (rh < 60 ? 1 : 2)) * 3
                           + (rw < 56 ? 0 : (rw < 60 ? 1 : 2));
        }

    f16x8 kf[4];
    #pragma unroll
    for (int mt = 0; mt < 4; ++mt)
        kf[mt] = *(const f16x8*)(kp + (mt * 16 + qc) * 32 + g * 8);

    #pragma unroll
    for (int nt = 0; nt < 4; ++nt) {
        int q = nt * 16 + qc;
        int rqh = wy * 8 + (q >> 3), rqw = wx * 8 + (q & 7);
        int rq = (rqh < 56 ? 0 : (rqh < 60 ? 1 : 2)) * 3
               + (rqw < 56 ? 0 : (rqw < 60 ? 1 : 2));
        f16x8 qf = *(const f16x8*)(qp + q * 32 + g * 8);

        f32x4 s[4];
        #pragma unroll
        for (int mt = 0; mt < 4; ++mt) {
            f32x4 z = {0.0f, 0.0f, 0.0f, 0.0f};
            s[mt] = __builtin_amdgcn_mfma_f32_16x16x32_f16(kf[mt], qf, z, 0, 0, 0);
        }

        float vals[16];
        #pragma unroll
        for (int mt = 0; mt < 4; ++mt) {
            float4 bv4 = *(const float4*)(rb + q * 64 + mt * 16 + g * 4);
            vals[mt * 4 + 0] = s[mt][0] + bv4.x + (rk[mt * 4 + 0] != rq ? -100.0f : 0.0f);
            vals[mt * 4 + 1] = s[mt][1] + bv4.y + (rk[mt * 4 + 1] != rq ? -100.0f : 0.0f);
            vals[mt * 4 + 2] = s[mt][2] + bv4.z + (rk[mt * 4 + 2] != rq ? -100.0f : 0.0f);
            vals[mt * 4 + 3] = s[mt][3] + bv4.w + (rk[mt * 4 + 3] != rq ? -100.0f : 0.0f);
        }

        float mx = vals[0];
        #pragma unroll
        for (int i = 1; i < 16; ++i) mx = fmaxf(mx, vals[i]);
        mx = fmaxf(mx, __shfl_xor(mx, 16));
        mx = fmaxf(mx, __shfl_xor(mx, 32));

        float sum = 0.0f;
        #pragma unroll
        for (int i = 0; i < 16; ++i) { vals[i] = __expf(vals[i] - mx); sum += vals[i]; }
        sum += __shfl_xor(sum, 16);
        sum += __shfl_xor(sum, 32);
        float inv = 1.0f / sum;

        #pragma unroll
        for (int mt = 0; mt < 4; ++mt) {
            union { _Float16 x[4]; uint2 u; } pk4;
            #pragma unroll
            for (int j = 0; j < 4; ++j) pk4.x[j] = (_Float16)(vals[mt * 4 + j] * inv);
            int off = (mt * 32 + g * 8) ^ ((q & 7) << 4);
            *(uint2*)(P + q * 128 + off) = pk4.u;
        }
    }

    f16x8 pa[4][2];
    #pragma unroll
    for (int im = 0; im < 4; ++im)
        #pragma unroll
        for (int ks = 0; ks < 2; ++ks) {
            int row = im * 16 + qc;
            int off = (ks * 64 + g * 16) ^ ((row & 7) << 4);
            pa[im][ks] = *(const f16x8*)(P + row * 128 + off);
        }
    f16x8 bvv[2][2];
    #pragma unroll
    for (int in = 0; in < 2; ++in)
        #pragma unroll
        for (int ks = 0; ks < 2; ++ks)
            bvv[in][ks] = *(const f16x8*)(vp + (in * 16 + qc) * 64 + ks * 32 + g * 8);

    f32x4 acc[4][2];
    #pragma unroll
    for (int im = 0; im < 4; ++im)
        #pragma unroll
        for (int in = 0; in < 2; ++in) {
            f32x4 z = {0.0f, 0.0f, 0.0f, 0.0f};
            acc[im][in] = z;
        }
    #pragma unroll
    for (int im = 0; im < 4; ++im)
        #pragma unroll
        for (int in = 0; in < 2; ++in) {
            acc[im][in] = __builtin_amdgcn_mfma_f32_16x16x32_f16(pa[im][0], bvv[in][0], acc[im][in], 0, 0, 0);
            acc[im][in] = __builtin_amdgcn_mfma_f32_16x16x32_f16(pa[im][1], bvv[in][1], acc[im][in], 0, 0, 0);
        }

    __syncthreads();   // all P reads complete; safe to overlay aob/Bsb

    // ---------- attn epilogue -> aob (LDS, proj-A swizzled fp16) ----------
    // aob[row=token l][col=channel f]: byte = row*512 + ((f>>3 ^ row&7)<<4) + (f&7)*2
    char* aob = SH;            // 32 KB
    char* Bsb = SH + 32768;    // 32 KB (B stage for proj)
    #pragma unroll
    for (int im = 0; im < 4; ++im)
        #pragma unroll
        for (int in = 0; in < 2; ++in)
            #pragma unroll
            for (int j = 0; j < 4; ++j) {
                int row = im * 16 + g * 4 + j;
                int f = h * 32 + in * 16 + qc;
                *(_Float16*)(aob + row * 512 + ((((f >> 3) ^ (row & 7)) << 4) + (f & 7) * 2)) =
                    (_Float16)acc[im][in][j];
            }
    __syncthreads();

    // ---------- phase 2: proj GEMM (64 x 256 @ 256 x 256) ----------
    int w04 = h & 3, wm = h >> 2;      // oc quarter, M half
    const char* wcp = (const char*)pwh;
    int bidx = n >> 6;

    f32x4 pacc[2][4];
    #pragma unroll
    for (int m = 0; m < 2; ++m)
        #pragma unroll
        for (int nn = 0; nn < 4; ++nn) {
            f32x4 z = {0.0f, 0.0f, 0.0f, 0.0f};
            pacc[m][nn] = z;
        }

    for (int c = 0; c < 4; ++c) {
        #pragma unroll
        for (int r = 0; r < 4; ++r) {
            int pos = r * 512 + tid;          // 2048 slots: 256 rows x 8
            int nr = pos >> 3, uu = pos & 7;
            const char* src = wcp + (size_t)nr * 512 + c * 128 + ((uu ^ (nr & 7)) << 4);
            __builtin_amdgcn_global_load_lds(
                (const __attribute__((address_space(1))) unsigned int*)src,
                (__attribute__((address_space(3))) unsigned int*)(Bsb + pos * 16),
                16, 0, 0);
        }
        __syncthreads();

        f16x8 av2[2][2], bv2[4][2];
        #pragma unroll
        for (int m = 0; m < 2; ++m) {
            int row = wm * 32 + m * 16 + qc;
            #pragma unroll
            for (int ks = 0; ks < 2; ++ks) {
                int u = c * 8 + ks * 4 + g;
                av2[m][ks] = *(const f16x8*)(aob + row * 512 + ((u ^ (row & 7)) << 4));
            }
        }
        #pragma unroll
        for (int nn = 0; nn < 4; ++nn) {
            int oc = w04 * 64 + nn * 16 + qc;
            #pragma unroll
            for (int ks = 0; ks < 2; ++ks)
                bv2[nn][ks] = *(const f16x8*)(Bsb + oc * 128 + (((ks * 4 + g) ^ (oc & 7)) << 4));
        }
        #pragma unroll
        for (int m = 0; m < 2; ++m)
            #pragma unroll
            for (int nn = 0; nn < 4; ++nn) {
                pacc[m][nn] = __builtin_amdgcn_mfma_f32_16x16x32_f16(av2[m][0], bv2[nn][0], pacc[m][nn], 0, 0, 0);
                pacc[m][nn] = __builtin_amdgcn_mfma_f32_16x16x32_f16(av2[m][1], bv2[nn][1], pacc[m][nn], 0, 0, 0);
            }
        __syncthreads();
    }

    // ---------- proj epilogue: +bias, un-window + un-roll, fp16 feath ----------
    #pragma unroll
    for (int nn = 0; nn < 4; ++nn) {
        int f = w04 * 64 + nn * 16 + qc;
        float bias = proj_b[f];
        #pragma unroll
        for (int m = 0; m < 2; ++m) {
            #pragma unroll
            for (int j = 0; j < 4; ++j) {
                int px = wm * 32 + m * 16 + g * 4 + j;
                int rh = ((win >> 3) << 3) + (px >> 3);
                int rw = ((win & 7) << 3) + (px & 7);
                int p = (rh + 4) & 63;
                int qq = (rw + 4) & 63;
                feath[((size_t)(bidx * 64 + p) * 64 + qq) * 256 + f] =
                    (_Float16)(pacc[m][nn][j] + bias);
            }
        }
    }
}

// ---------------------------------------------------------------------------
// Fused bilinear-sample + conv, f16 MFMA implicit GEMM, v4 (pipelined) —
// unchanged from round 9 (66 us, best measured).
// ---------------------------------------------------------------------------
__global__ __launch_bounds__(512) void sample_conv_mfma4_kernel(
    const _Float16* __restrict__ feath, const float* __restrict__ ymap,
    const _Float16* __restrict__ wT2h, const float* __restrict__ dsc_b,
    float* __restrict__ out) {

    __shared__ __align__(16) char Ab[2][16384];   // 128 px * 128B
    __shared__ __align__(16) char Bb[2][32768];   // 256 oc * 128B
    __shared__ unsigned row0[2][9][64];
    __shared__ unsigned row1[2][9][64];
    __shared__ float    wyv[2][9][64];

    int blk = blockIdx.x;              // 0..255; XCD swizzle
    int b = blk & 7, wd0 = (blk >> 3) * 2;
    int tid = threadIdx.x;
    int lane = tid & 63, w = tid >> 6;
    int qc = lane & 15, g = lane >> 4;
    int ph = w >> 2, nq = w & 3;       // px half, oc quarter

    for (int idx = tid; idx < 1152; idx += 512) {
        int wdl = idx / 576;
        int r = idx - wdl * 576;
        int k = r >> 6, hd = r & 63;
        int wd = wd0 + wdl;
        float y = ymap[((size_t)(b * 576 + wd * 9 + k)) * 64 + hd];
        y = fminf(fmaxf(y, 0.0f), 63.0f);
        float y0f = floorf(y);
        int y0 = (int)y0f;
        int y1 = min(y0 + 1, 63);
        int xc = min(max(hd + k - 4, 0), 63);
        row0[wdl][k][hd] = (unsigned)(((b * 64 + y0) * 64 + xc) * 512);
        row1[wdl][k][hd] = (unsigned)(((b * 64 + y1) * 64 + xc) * 512);
        wyv[wdl][k][hd] = y - y0f;
    }

    f32x4 acc[4][4];
    #pragma unroll
    for (int m = 0; m < 4; ++m)
        #pragma unroll
        for (int n = 0; n < 4; ++n) {
            f32x4 z = {0.0f, 0.0f, 0.0f, 0.0f};
            acc[m][n] = z;
        }

    const char* featc = (const char*)feath;
    const char* wc    = (const char*)wT2h;

    int pxA[2], sAv[2];
    #pragma unroll
    for (int r = 0; r < 2; ++r) {
        int pos = r * 512 + tid;
        pxA[r] = pos >> 3;
        sAv[r] = pos & 7;
    }

    int rAa = qc * 128;
    int u0 = ((g    ) ^ (qc & 7)) << 4;
    int u1 = ((4 + g) ^ (qc & 7)) << 4;

    __syncthreads();

    #pragma unroll
    for (int r = 0; r < 4; ++r) {
        int pos = r * 512 + tid;
        int n = pos >> 3, uu = pos & 7;
        const char* src = wc + n * 4608 + 0 * 128 + ((uu ^ (n & 7)) << 4);
        __builtin_amdgcn_global_load_lds(
            (const __attribute__((address_space(1))) unsigned int*)src,
            (__attribute__((address_space(3))) unsigned int*)(Bb[0] + pos * 16),
            16, 0, 0);
    }
    #pragma unroll
    for (int r = 0; r < 2; ++r) {
        int px = pxA[r], sA = sAv[r];
        int wdl = px >> 6, hd = px & 63;
        unsigned b0 = row0[wdl][0][hd] + sA * 16;
        unsigned b1 = row1[wdl][0][hd] + sA * 16;
        float wy = wyv[wdl][0][hd];
        f16x8 v0 = *(const f16x8*)(featc + b0);
        f16x8 v1 = *(const f16x8*)(featc + b1);
        _Float16 wyh = (_Float16)wy;
        _Float16 omh = (_Float16)(1.0f - wy);
        f16x8 res = v0 * omh + v1 * wyh;
        *(f16x8*)(Ab[0] + px * 128 + ((sA ^ (px & 7)) << 4)) = res;
    }
    __syncthreads();

    for (int c = 0; c < 36; ++c) {
        int cur = c & 1, nxt = cur ^ 1;

        f16x8 s0[2], s1[2];
        float swy[2];
        if (c < 35) {
            int cn = c + 1;
            int ks = cn >> 2, cib = (cn & 3) * 128;
            #pragma unroll
            for (int r = 0; r < 4; ++r) {
                int pos = r * 512 + tid;
                int n = pos >> 3, uu = pos & 7;
                const char* src = wc + n * 4608 + cn * 128 + ((uu ^ (n & 7)) << 4);
                __builtin_amdgcn_global_load_lds(
                    (const __attribute__((address_space(1))) unsigned int*)src,
                    (__attribute__((address_space(3))) unsigned int*)(Bb[nxt] + pos * 16),
                    16, 0, 0);
            }
            #pragma unroll
            for (int r = 0; r < 2; ++r) {
                int px = pxA[r], sA = sAv[r];
                int wdl = px >> 6, hd = px & 63;
                unsigned b0 = row0[wdl][ks][hd] + cib + sA * 16;
                unsigned b1 = row1[wdl][ks][hd] + cib + sA * 16;
                swy[r] = wyv[wdl][ks][hd];
                s0[r] = *(const f16x8*)(featc + b0);
                s1[r] = *(const f16x8*)(featc + b1);
            }
        }

        f16x8 av[4][2], bv[4][2];
        #pragma unroll
        for (int m = 0; m < 4; ++m) {
            char* abase = Ab[cur] + ph * 8192 + m * 2048 + rAa;
            av[m][0] = *(const f16x8*)(abase + u0);
            av[m][1] = *(const f16x8*)(abase + u1);
        }
        #pragma unroll
        for (int n = 0; n < 4; ++n) {
            char* bbase = Bb[cur] + nq * 8192 + n * 2048 + rAa;
            bv[n][0] = *(const f16x8*)(bbase + u0);
            bv[n][1] = *(const f16x8*)(bbase + u1);
        }
        #pragma unroll
        for (int m = 0; m < 4; ++m)
            #pragma unroll
            for (int n = 0; n < 4; ++n) {
                acc[m][n] = __builtin_amdgcn_mfma_f32_16x16x32_f16(av[m][0], bv[n][0], acc[m][n], 0, 0, 0);
                acc[m][n] = __builtin_amdgcn_mfma_f32_16x16x32_f16(av[m][1], bv[n][1], acc[m][n], 0, 0, 0);
            }

        if (c < 35) {
            #pragma unroll
            for (int r = 0; r < 2; ++r) {
                int px = pxA[r], sA = sAv[r];
                _Float16 wyh = (_Float16)swy[r];
                _Float16 omh = (_Float16)(1.0f - swy[r]);
                f16x8 res = s0[r] * omh + s1[r] * wyh;
                *(f16x8*)(Ab[nxt] + px * 128 + ((sA ^ (px & 7)) << 4)) = res;
            }
        }
        __syncthreads();
    }

    #pragma unroll
    for (int n = 0; n < 4; ++n) {
        int o = nq * 64 + n * 16 + qc;
        float bvs = dsc_b[o];
        float* orow = out + ((size_t)(b * 256 + o) * 64 + (wd0 + ph)) * 64;
        #pragma unroll
        for (int m = 0; m < 4; ++m) {
            int px = m * 16 + g * 4;
            float4 res;
            res.x = fmaxf(acc[m][n][0] + bvs, 0.0f);
            res.y = fmaxf(acc[m][n][1] + bvs, 0.0f);
            res.z = fmaxf(acc[m][n][2] + bvs, 0.0f);
            res.w = fmaxf(acc[m][n][3] + bvs, 0.0f);
            *(float4*)(orow + px) = res;
        }
    }
}

// ---------------------------------------------------------------------------
extern "C" void kernel_launch(void* const* d_in, const int* in_sizes, int n_in,
                              void* d_out, int out_size, void* d_ws, size_t ws_size,
                              hipStream_t stream) {
    (void)in_sizes; (void)n_in; (void)out_size; (void)ws_size;
    const float* x        = (const float*)d_in[0];
    const float* qkv_w    = (const float*)d_in[1];
    const float* qkv_b    = (const float*)d_in[2];
    const float* proj_w   = (const float*)d_in[3];
    const float* proj_b   = (const float*)d_in[4];
    const float* rel_bias = (const float*)d_in[5];
    const float* offset   = (const float*)d_in[6];
    const float* dsc_w    = (const float*)d_in[7];
    const float* dsc_b    = (const float*)d_in[8];
    float* out = (float*)d_out;

    unsigned short* wsu = (unsigned short*)d_ws;
    _Float16* qh = (_Float16*)wsu;                                  // 8.39M fp16
    _Float16* kh = (_Float16*)(wsu + NFLOAT_BUF);
    _Float16* vt = (_Float16*)(wsu + 2 * (size_t)NFLOAT_BUF);
    _Float16* feath = (_Float16*)(wsu + 3 * (size_t)NFLOAT_BUF);    // fp16
    unsigned short* xb      = wsu + 4 * (size_t)NFLOAT_BUF;         // bf16
    unsigned short* wb      = wsu + 5 * (size_t)NFLOAT_BUF;         // 196608 bf16
    _Float16* pwh           = (_Float16*)(wb + 196608);             // 65536 fp16
    _Float16* wT2h          = (_Float16*)((unsigned short*)pwh + 65536);  // 589824 fp16
    float* ymap = (float*)((unsigned short*)wT2h + 589824);         // 294912 f32

    prep_kernel<<<6656, 256, 0, stream>>>(x, xb, qkv_w, wb, proj_w, pwh,
                                          dsc_w, wT2h, offset, ymap);
    qkv_mfma_kernel<<<dim3(3, 512), 256, 0, stream>>>(xb, wb, qkv_b, qh, kh, vt);
    attn_proj_kernel<<<512, 512, 0, stream>>>(qh, kh, vt, rel_bias, pwh, proj_b, feath);
    sample_conv_mfma4_kernel<<<256, 512, 0, stream>>>(feath, ymap, wT2h, dsc_b, out);
}